// Round 4
// baseline (354.557 us; speedup 1.0000x reference)
//
#include <hip/hip_runtime.h>
#include <cstddef>

typedef unsigned short u16;
typedef __bf16 bf16x8 __attribute__((ext_vector_type(8)));
typedef float f32x4 __attribute__((ext_vector_type(4)));
typedef u16 u16x8 __attribute__((ext_vector_type(8)));

__device__ __forceinline__ u16 f2bf(float f) {
  unsigned u = __builtin_bit_cast(unsigned, f);
  u += 0x7fffu + ((u >> 16) & 1u);   // round-to-nearest-even
  return (u16)(u >> 16);
}
__device__ __forceinline__ float bf2f(u16 h) {
  return __builtin_bit_cast(float, ((unsigned)h) << 16);
}
__device__ __forceinline__ void gld_lds16(const void* g, void* l) {
  __builtin_amdgcn_global_load_lds((const __attribute__((address_space(1))) void*)g,
                                   (__attribute__((address_space(3))) void*)l, 16, 0, 0);
}

// ---------------- f32 -> bf16 conversion, 8 elems/thread ----------------
__global__ __launch_bounds__(256) void cvt_kernel(const float* __restrict__ in,
                                                  u16* __restrict__ out, int n) {
  int i = (blockIdx.x * 256 + threadIdx.x) * 8;
  if (i >= n) return;
  f32x4 a = *(const f32x4*)(in + i);
  f32x4 b = *(const f32x4*)(in + i + 4);
  u16x8 o;
  o[0] = f2bf(a[0]); o[1] = f2bf(a[1]); o[2] = f2bf(a[2]); o[3] = f2bf(a[3]);
  o[4] = f2bf(b[0]); o[5] = f2bf(b[1]); o[6] = f2bf(b[2]); o[7] = f2bf(b[3]);
  *(u16x8*)(out + i) = o;
}

// =====================================================================
// Pipelined 256xBN B^T GEMM.  C[m][n] = sum_k A[m][k]*B[n][k].
// 512 threads, 8 waves (2M x 4N), K-tile 64 (2 halves of 32).
// Per K-tile: free-running {24 ds_read_b128 + 64 MFMA} interleave,
// then lgkm(0)+barrier; stage(t+2); counted vmcnt; barrier.  2-slot ring.
// Conflict-free LDS: half-tile = 64 super-rows x 256B; 16B slot of
// (row, k-slot c) at p=(row&3)*4 + (c ^ ((row>>2)&3)).
// EPI: 0 qp-proj  1 kp-proj  2 vpt-proj(transposed via LDS)
//      3 scores plain  4 PV plain
//      6 scores P=exp(s*scale)+rowsum-L(atomic)  7 PV /L
// =====================================================================
template<int BN, int EPI>
__global__ __launch_bounds__(512, 2) void gemm_pipe(
    const u16* __restrict__ A, const u16* __restrict__ B, u16* __restrict__ C,
    const float* __restrict__ bias, float* __restrict__ Lbuf,
    int N, int K, float scale, long bsA, long bsB, long bsC)
{
  constexpr int BM = 256;
  constexpr int WN = BN / 4, FN = WN / 16;   // per-wave cols, 16-col frags
  constexpr int AHB = 16384;                 // A half-tile bytes (256r x 32k x 2B)
  constexpr int BHB = BN * 32 * 2;           // B half-tile bytes
  constexpr int BLOADS = BHB / 8192;         // gld_lds/thread per B half (2 or 1)
  constexpr int TLOADS = 4 + 2 * BLOADS;     // gld_lds/thread per tile
  constexpr int STAGEB = 4 * AHB + 4 * BHB;
  constexpr int EPIB = (EPI == 2) ? 256 * 129 * 2 : 0;
  __shared__ alignas(16) char smem[(STAGEB > EPIB) ? STAGEB : EPIB];

  const int tid = threadIdx.x, lid = tid & 63, wid = tid >> 6;
  const int wm = wid >> 2, wn = wid & 3;
  const int g = lid >> 4, r16 = lid & 15;

  // XCD-aware swizzle: consecutive slots on one XCD sweep all x (shared A panel)
  const int nx = gridDim.x, ny = gridDim.y;
  const int lin = blockIdx.x + nx * (blockIdx.y + ny * blockIdx.z);
  const int xcd = lin & 7, slot = lin >> 3;
  const int wx = slot % nx;
  const int c_ = xcd + (slot / nx) * 8;
  const int m0 = (c_ % ny) * BM, n0 = wx * BN, z = c_ / ny;

  A += (size_t)z * bsA;
  B += (size_t)z * bsB;
  const int NT = K >> 6;

  // swizzled byte offset within a half-tile slot for (row, k-slot g)
  auto swzoff = [](int row, int gg) {
    return (row >> 2) * 256 + ((((row & 3) << 2) | (gg ^ ((row >> 2) & 3))) << 4);
  };
  int offA[2][4], offB2[FN];
#pragma unroll
  for (int cf = 0; cf < 2; ++cf)
#pragma unroll
    for (int f = 0; f < 4; ++f)
      offA[cf][f] = swzoff(wm * 128 + cf * 64 + f * 16 + r16, g);
#pragma unroll
  for (int f = 0; f < FN; ++f)
    offB2[f] = swzoff(wn * WN + f * 16 + r16, g);

  // stage one full K-tile (both halves, A and B); linear LDS dest, permuted src
  auto stage_tile = [&](int ts) {
    const int buf = ts & 1;
    const u16* At = A + (size_t)ts * 64;
    const u16* Bt = B + (size_t)ts * 64;
    const int pos = tid & 15, pr = pos >> 2, sup0 = tid >> 4;
#pragma unroll
    for (int ks = 0; ks < 2; ++ks) {
      char* Ad = smem + buf * (2 * AHB) + ks * AHB;
#pragma unroll
      for (int l = 0; l < 2; ++l) {
        int sup = l * 32 + sup0;
        int row = sup * 4 + pr;
        int cd = (pos & 3) ^ (sup & 3);
        gld_lds16(At + (size_t)(m0 + row) * K + ks * 32 + cd * 8,
                  Ad + l * 8192 + tid * 16);
      }
      char* Bd = smem + 4 * AHB + buf * (2 * BHB) + ks * BHB;
#pragma unroll
      for (int l = 0; l < BLOADS; ++l) {
        int sup = l * 32 + sup0;
        int row = sup * 4 + pr;
        int cd = (pos & 3) ^ (sup & 3);
        gld_lds16(Bt + (size_t)(n0 + row) * K + ks * 32 + cd * 8,
                  Bd + l * 8192 + tid * 16);
      }
    }
  };

  f32x4 acc[8][FN];
#pragma unroll
  for (int i = 0; i < 8; ++i)
#pragma unroll
    for (int j = 0; j < FN; ++j) acc[i][j] = 0.0f;

  // prologue: stage tiles 0,1; wait tile0 landed (tile1 stays in flight)
  stage_tile(0);
  if (NT > 1) {
    stage_tile(1);
    if constexpr (TLOADS == 8) asm volatile("s_waitcnt vmcnt(8)" ::: "memory");
    else                       asm volatile("s_waitcnt vmcnt(6)" ::: "memory");
  } else {
    asm volatile("s_waitcnt vmcnt(0)" ::: "memory");
  }
  __builtin_amdgcn_s_barrier();

  for (int t = 0; t < NT; ++t) {
    const char* ab = smem + (t & 1) * (2 * AHB);
    const char* bb = smem + 4 * AHB + (t & 1) * (2 * BHB);
#pragma unroll
    for (int ks = 0; ks < 2; ++ks) {
      bf16x8 br[FN];
#pragma unroll
      for (int f = 0; f < FN; ++f) br[f] = *(const bf16x8*)(bb + ks * BHB + offB2[f]);
#pragma unroll
      for (int cf = 0; cf < 2; ++cf) {
        bf16x8 ar[4];
#pragma unroll
        for (int f = 0; f < 4; ++f) ar[f] = *(const bf16x8*)(ab + ks * AHB + offA[cf][f]);
        __builtin_amdgcn_s_setprio(1);
#pragma unroll
        for (int f = 0; f < 4; ++f)
#pragma unroll
          for (int n = 0; n < FN; ++n)
            acc[cf * 4 + f][n] =
                __builtin_amdgcn_mfma_f32_16x16x32_bf16(ar[f], br[n], acc[cf * 4 + f][n], 0, 0, 0);
        __builtin_amdgcn_s_setprio(0);
      }
    }
    // all my reads of buf[t&1] done; collective point, then overwrite it
    asm volatile("s_waitcnt lgkmcnt(0)" ::: "memory");
    __builtin_amdgcn_s_barrier();
    if (t + 2 < NT) {
      stage_tile(t + 2);
      // leave only t+2's loads outstanding -> t+1 certified landed
      if constexpr (TLOADS == 8) asm volatile("s_waitcnt vmcnt(8)" ::: "memory");
      else                       asm volatile("s_waitcnt vmcnt(6)" ::: "memory");
    } else {
      asm volatile("s_waitcnt vmcnt(0)" ::: "memory");
    }
    __builtin_amdgcn_s_barrier();
  }

  // ---------------- epilogues ----------------
  const size_t cb = (size_t)z * bsC;
  if constexpr (EPI == 6) {
    float* Lp = Lbuf + (size_t)z * 4096;
#pragma unroll
    for (int mf = 0; mf < 8; ++mf) {
#pragma unroll
      for (int r = 0; r < 4; ++r) {
        int gm = m0 + wm * 128 + mf * 16 + (g << 2) + r;
        float rs = 0.0f;
#pragma unroll
        for (int nf = 0; nf < FN; ++nf) {
          int gn = n0 + wn * WN + nf * 16 + r16;
          float p = __expf(acc[mf][nf][r] * scale);
          u16 pb = f2bf(p);
          rs += bf2f(pb);
          C[cb + (size_t)gm * N + gn] = pb;
        }
        rs += __shfl_xor(rs, 1); rs += __shfl_xor(rs, 2);
        rs += __shfl_xor(rs, 4); rs += __shfl_xor(rs, 8);
        if (r16 == 0) atomicAdd(&Lp[gm], rs);
      }
    }
  } else if constexpr (EPI == 7) {
    const float* Lp = Lbuf + (size_t)z * 4096;
#pragma unroll
    for (int mf = 0; mf < 8; ++mf) {
#pragma unroll
      for (int r = 0; r < 4; ++r) {
        int gm = m0 + wm * 128 + mf * 16 + (g << 2) + r;
        float inv = 1.0f / Lp[gm];
#pragma unroll
        for (int nf = 0; nf < FN; ++nf) {
          int gn = n0 + wn * WN + nf * 16 + r16;
          C[cb + (size_t)(gm >> 3) * 4096 + (size_t)(gm & 7) * 512 + gn] =
              f2bf(acc[mf][nf][r] * inv);
        }
      }
    }
  } else if constexpr (EPI == 0 || EPI == 1) {
#pragma unroll
    for (int mf = 0; mf < 8; ++mf)
#pragma unroll
      for (int nf = 0; nf < FN; ++nf)
#pragma unroll
        for (int r = 0; r < 4; ++r) {
          int gm = m0 + wm * 128 + mf * 16 + (g << 2) + r;
          int gn = n0 + wn * WN + nf * 16 + r16;
          float val = acc[mf][nf][r] + bias[gn];
          int b = gm >> 9, s = gm & 511, hh = gn >> 9, d2 = gn & 511;
          if constexpr (EPI == 0)
            C[(size_t)b * 2097152 + (size_t)((s << 3) + hh) * 512 + d2] = f2bf(val);
          else
            C[(size_t)b * 2097152 + (size_t)((hh << 9) + s) * 512 + d2] = f2bf(val);
        }
  } else if constexpr (EPI == 2) {
    u16* E = (u16*)smem;   // 256 x 129
#pragma unroll
    for (int mf = 0; mf < 8; ++mf)
#pragma unroll
      for (int nf = 0; nf < FN; ++nf)
#pragma unroll
        for (int r = 0; r < 4; ++r) {
          int lm = wm * 128 + mf * 16 + (g << 2) + r;
          int ln = wn * WN + nf * 16 + r16;
          E[lm * 129 + ln] = f2bf(acc[mf][nf][r] + bias[n0 + ln]);
        }
    __syncthreads();
    int b = m0 >> 9, s0 = m0 & 511, hh = n0 >> 9, d20 = n0 & 511;
    int c = tid >> 2;            // 0..127 local col (d2)
    int r0 = (tid & 3) * 64;     // quarter of 256 rows (s)
    u16* dst = C + (size_t)b * 2097152 + (size_t)(d20 + c) * 4096 + (hh << 9) + s0 + r0;
#pragma unroll
    for (int i = 0; i < 64; i += 8) {
      u16x8 p;
#pragma unroll
      for (int jj = 0; jj < 8; ++jj) p[jj] = E[(r0 + i + jj) * 129 + c];
      *(u16x8*)(dst + i) = p;
    }
  } else {
#pragma unroll
    for (int mf = 0; mf < 8; ++mf)
#pragma unroll
      for (int nf = 0; nf < FN; ++nf)
#pragma unroll
        for (int r = 0; r < 4; ++r) {
          int gm = m0 + wm * 128 + mf * 16 + (g << 2) + r;
          int gn = n0 + wn * WN + nf * 16 + r16;
          float v = acc[mf][nf][r];
          if constexpr (EPI == 3)
            C[cb + (size_t)gm * N + gn] = f2bf(v * scale);
          else
            C[cb + (size_t)(gm >> 3) * 4096 + (size_t)(gm & 7) * 512 + gn] = f2bf(v);
        }
  }
}

// ---------------- generic B^T GEMM (final projection), 64x64 tile ----------------
template<int BM, int BN, int EPI>
__global__ __launch_bounds__(256) void gemm_bt(
    const u16* __restrict__ A, const u16* __restrict__ B, void* __restrict__ Cv,
    const float* __restrict__ bias, int M, int N, int K, float scale,
    long bsA, long bsB, long bsC)
{
  constexpr int BK = 64;
  constexpr int WMT = BM / 2, WNT = BN / 2;
  constexpr int FM = BM / 32, FN = BN / 32;
  __shared__ alignas(16) char smem[(BM + BN) * BK * 2];
  u16* As = (u16*)smem;
  u16* Bs = As + BM * BK;

  const int tid = threadIdx.x;
  const int lid = tid & 63, wid = tid >> 6;
  const int m0 = blockIdx.y * BM, n0 = blockIdx.x * BN;
  const int z = blockIdx.z;
  A += (size_t)z * bsA;
  B += (size_t)z * bsB;
  (void)M;

  const int wm = wid >> 1, wn = wid & 1;

  f32x4 acc[FM][FN];
#pragma unroll
  for (int i = 0; i < FM; ++i)
#pragma unroll
    for (int j = 0; j < FN; ++j) acc[i][j] = 0.0f;

  const int rA = lid >> 3;
  const int ke = (lid & 7) * 8;

  const int nK = K / BK;
  for (int kt = 0; kt < nK; ++kt) {
    const int k0 = kt * BK;
#pragma unroll
    for (int c = 0; c < BM / 32; ++c) {
      int chunk = wid * (BM / 32) + c;
      const u16* src = A + (size_t)(m0 + chunk * 8 + rA) * K + k0 + ke;
      gld_lds16(src, (char*)As + chunk * 1024);
    }
#pragma unroll
    for (int c = 0; c < BN / 32; ++c) {
      int chunk = wid * (BN / 32) + c;
      const u16* src = B + (size_t)(n0 + chunk * 8 + rA) * K + k0 + ke;
      gld_lds16(src, (char*)Bs + chunk * 1024);
    }
    __syncthreads();

#pragma unroll
    for (int kc = 0; kc < 2; ++kc) {
      bf16x8 af[FM], bfv[FN];
      const int kb = kc * 32 + (lid >> 4) * 8;
#pragma unroll
      for (int i = 0; i < FM; ++i)
        af[i] = *(const bf16x8*)&As[(wm * WMT + i * 16 + (lid & 15)) * BK + kb];
#pragma unroll
      for (int j = 0; j < FN; ++j)
        bfv[j] = *(const bf16x8*)&Bs[(wn * WNT + j * 16 + (lid & 15)) * BK + kb];
#pragma unroll
      for (int i = 0; i < FM; ++i)
#pragma unroll
        for (int j = 0; j < FN; ++j)
          acc[i][j] = __builtin_amdgcn_mfma_f32_16x16x32_bf16(af[i], bfv[j], acc[i][j], 0, 0, 0);
    }
    __syncthreads();
  }

#pragma unroll
  for (int i = 0; i < FM; ++i)
#pragma unroll
    for (int j = 0; j < FN; ++j)
#pragma unroll
      for (int r = 0; r < 4; ++r) {
        int lm = wm * WMT + i * 16 + ((lid >> 4) << 2) + r;
        int ln = wn * WNT + j * 16 + (lid & 15);
        int gm = m0 + lm, gn = n0 + ln;
        float* Cp = (float*)Cv;
        Cp[(size_t)gm * N + gn] = acc[i][j][r] + bias[gn];
      }
  (void)scale; (void)bsC;
}

// ---------------- row softmax over 4096 bf16, in place (fallback only) ----------------
__global__ __launch_bounds__(256) void softmax_kernel(u16* __restrict__ S) {
  const size_t row = blockIdx.x;
  u16* p = S + row * 4096;
  const int t = threadIdx.x;
  float v[16];
#pragma unroll
  for (int i = 0; i < 2; ++i) {
    u16x8 x = *(const u16x8*)(p + i * 2048 + t * 8);
#pragma unroll
    for (int j = 0; j < 8; ++j) v[i * 8 + j] = bf2f(x[j]);
  }
  float m = v[0];
#pragma unroll
  for (int i = 1; i < 16; ++i) m = fmaxf(m, v[i]);
#pragma unroll
  for (int o = 32; o; o >>= 1) m = fmaxf(m, __shfl_xor(m, o));
  __shared__ float red[8];
  int w = t >> 6;
  if ((t & 63) == 0) red[w] = m;
  __syncthreads();
  m = fmaxf(fmaxf(red[0], red[1]), fmaxf(red[2], red[3]));
  float sum = 0.0f;
#pragma unroll
  for (int i = 0; i < 16; ++i) { v[i] = __expf(v[i] - m); sum += v[i]; }
#pragma unroll
  for (int o = 32; o; o >>= 1) sum += __shfl_xor(sum, o);
  __syncthreads();
  if ((t & 63) == 0) red[4 + w] = sum;
  __syncthreads();
  sum = red[4] + red[5] + red[6] + red[7];
  float inv = 1.0f / sum;
#pragma unroll
  for (int i = 0; i < 2; ++i) {
    u16x8 x;
#pragma unroll
    for (int j = 0; j < 8; ++j) x[j] = f2bf(v[i * 8 + j] * inv);
    *(u16x8*)(p + i * 2048 + t * 8) = x;
  }
}

// ---------------------------------------------------------------------------
extern "C" void kernel_launch(void* const* d_in, const int* in_sizes, int n_in,
                              void* d_out, int out_size, void* d_ws, size_t ws_size,
                              hipStream_t stream) {
  (void)in_sizes; (void)n_in; (void)out_size;
  const float* q_f  = (const float*)d_in[0];
  const float* k_f  = (const float*)d_in[1];
  const float* v_f  = (const float*)d_in[2];
  const float* wq_b = (const float*)d_in[4];
  const float* wk_b = (const float*)d_in[6];
  const float* wv_b = (const float*)d_in[8];
  const float* ou_b = (const float*)d_in[10];
  float* out = (float*)d_out;

  char* ws = (char*)d_ws;
  u16* q_bf  = (u16*)(ws + 0);
  u16* k_bf  = (u16*)(ws + 2097152);
  u16* v_bf  = (u16*)(ws + 4194304);
  u16* wA_q  = (u16*)(ws + 6291456);    // bf16(wk_w)  (reference swaps wk<->wq)
  u16* wA_k  = (u16*)(ws + 10485760);   // bf16(wq_w)
  u16* wA_v  = (u16*)(ws + 14680064);   // bf16(wv_w)
  u16* ow_bf = (u16*)(ws + 18874368);   // bf16(out_w)
  u16* qp    = (u16*)(ws + 23068672);   // (4, 4096, 512) bf16, l = s*8+h
  u16* kp    = (u16*)(ws + 39845888);   // (4, 4096, 512) bf16, l' = h*512+s
  u16* vpt   = (u16*)(ws + 56623104);   // (4, 512, 4096) bf16, [d2][l']
  u16* oflat = (u16*)(ws + 73400320);   // (4, 512, 4096) bf16 (= o reshaped)
  u16* sc    = (u16*)(ws + 90177536);   // P = exp(scores*scl) bf16
  bool full = ws_size >= (size_t)90177536 + 134217728;

  // L row-sum buffer: first 64KB of d_out (dead until final GEMM overwrites it).
  float* L = (float*)d_out;

  // f32 -> bf16 converts
  cvt_kernel<<<512,  256, 0, stream>>>(q_f, q_bf, 1048576);
  cvt_kernel<<<512,  256, 0, stream>>>(k_f, k_bf, 1048576);
  cvt_kernel<<<512,  256, 0, stream>>>(v_f, v_bf, 1048576);
  cvt_kernel<<<1024, 256, 0, stream>>>((const float*)d_in[5], wA_q, 2097152);
  cvt_kernel<<<1024, 256, 0, stream>>>((const float*)d_in[3], wA_k, 2097152);
  cvt_kernel<<<1024, 256, 0, stream>>>((const float*)d_in[7], wA_v, 2097152);
  cvt_kernel<<<1024, 256, 0, stream>>>((const float*)d_in[9], ow_bf, 2097152);

  // projections (note reference swap: qp uses wk, kp uses wq)
  gemm_pipe<128,0><<<dim3(32,8,1), 512, 0, stream>>>(q_bf, wA_q, qp,  wk_b, nullptr, 4096,512, 1.f, 0,0,0);
  gemm_pipe<128,1><<<dim3(32,8,1), 512, 0, stream>>>(k_bf, wA_k, kp,  wq_b, nullptr, 4096,512, 1.f, 0,0,0);
  gemm_pipe<128,2><<<dim3(32,8,1), 512, 0, stream>>>(v_bf, wA_v, vpt, wv_b, nullptr, 4096,512, 1.f, 0,0,0);

  const float scl = 0.04419417382415922f;  // 1/sqrt(512)
  if (full) {
    hipMemsetAsync(L, 0, 65536, stream);
    // scores: P = exp(s*scl), row-sums into L
    gemm_pipe<256,6><<<dim3(16,16,4), 512, 0, stream>>>(qp, kp, sc, nullptr, L, 4096, 512, scl,
                                                        2097152, 2097152, 16777216);
    // PV: O = (P @ V) / L
    gemm_pipe<128,7><<<dim3(4,16,4), 512, 0, stream>>>(sc, vpt, oflat, nullptr, L, 512, 4096, 1.f,
                                                       16777216, 2097152, 2097152);
  } else {
    for (int b = 0; b < 4; ++b) {
      gemm_pipe<256,3><<<dim3(16,16,1), 512, 0, stream>>>(qp + b*2097152, kp + b*2097152, sc,
                                                          nullptr, nullptr, 4096, 512, scl, 0,0,0);
      softmax_kernel<<<4096, 256, 0, stream>>>(sc);
      gemm_pipe<128,4><<<dim3(4,16,1), 512, 0, stream>>>(sc, vpt + b*2097152, oflat + b*2097152,
                                                         nullptr, nullptr, 512, 4096, 1.f, 0,0,0);
    }
  }
  // final projection, f32 output
  gemm_bt<64,64,5><<<dim3(8,32,1), 256, 0, stream>>>(oflat, ow_bf, out, ou_b, 2048,512,4096, 1.f, 0,0,0);
}

// Round 6
// 287.299 us; speedup vs baseline: 1.2341x; 1.2341x over previous
//
#include <hip/hip_runtime.h>
#include <cstddef>

typedef unsigned short u16;
typedef unsigned char u8;
typedef float f32x4 __attribute__((ext_vector_type(4)));
typedef u16 u16x8 __attribute__((ext_vector_type(8)));
typedef __bf16 bf16x8 __attribute__((ext_vector_type(8)));

__device__ __forceinline__ u16 f2bf(float f) {
  unsigned u = __builtin_bit_cast(unsigned, f);
  u += 0x7fffu + ((u >> 16) & 1u);   // RTNE
  return (u16)(u >> 16);
}
__device__ __forceinline__ float bf2f(u16 h) {
  return __builtin_bit_cast(float, ((unsigned)h) << 16);
}
__device__ __forceinline__ u8 f2fp8(float v) {
  int t = __builtin_amdgcn_cvt_pk_fp8_f32(v, v, 0, false);
  return (u8)(t & 0xff);
}
__device__ __forceinline__ void gld_lds16(const void* g, void* l) {
  __builtin_amdgcn_global_load_lds((const __attribute__((address_space(1))) void*)g,
                                   (__attribute__((address_space(3))) void*)l, 16, 0, 0);
}

// ---------------- f32 -> bf16, 8 elems/thread ----------------
__global__ __launch_bounds__(256) void cvt_kernel(const float* __restrict__ in,
                                                  u16* __restrict__ out, int n) {
  int i = (blockIdx.x * 256 + threadIdx.x) * 8;
  if (i >= n) return;
  f32x4 a = *(const f32x4*)(in + i);
  f32x4 b = *(const f32x4*)(in + i + 4);
  u16x8 o;
  o[0] = f2bf(a[0]); o[1] = f2bf(a[1]); o[2] = f2bf(a[2]); o[3] = f2bf(a[3]);
  o[4] = f2bf(b[0]); o[5] = f2bf(b[1]); o[6] = f2bf(b[2]); o[7] = f2bf(b[3]);
  *(u16x8*)(out + i) = o;
}

// =====================================================================
// bf16 pipelined 128x128 B^T GEMM.  256 thr, 4 waves (2M x 2N), K-tile 64.
// LDS 64KB (2 bufs x [A 2ks x 128r x 64B | B same]) -> 2 blocks/CU.
// Conflict-free swizzle: 16B slot x of (row,g): x = g ^ ((row>>1)&3);
// staged with inverse-permuted global source, linear base+lane*16 dest.
// EPI: 0 qp-proj -> fp8   1 kp-proj -> fp8   2 vpt-proj bf16 transposed
//      7 PV /L -> oflat bf16
// =====================================================================
template<int EPI>
__global__ __launch_bounds__(256, 2) void gemm_bf(
    const u16* __restrict__ A, const u16* __restrict__ B, void* __restrict__ Cv,
    const float* __restrict__ bias, const float* __restrict__ Lbuf,
    int N, int K, long bsA, long bsB, long bsC)
{
  __shared__ alignas(16) char smem[65536];

  const int tid = threadIdx.x, lid = tid & 63, wid = tid >> 6;
  const int wm = wid >> 1, wn = wid & 1;
  const int g = lid >> 4, r16 = lid & 15;

  // XCD-aware bijective swizzle (grids are multiples of 8)
  const int nx = gridDim.x, ny = gridDim.y;
  const int lin = blockIdx.x + nx * (blockIdx.y + ny * blockIdx.z);
  const int xcd = lin & 7, slot = lin >> 3;
  const int wx = slot % nx;
  const int c_ = xcd + (slot / nx) * 8;
  const int m0 = (c_ % ny) * 128, n0 = wx * 128, z = c_ / ny;

  A += (size_t)z * bsA;
  B += (size_t)z * bsB;
  const int NT = K >> 6;

  // frag byte offsets within a ks-half (8KB): row*64 + (g^((row>>1)&3))*16
  int offA[4], offB[4];
#pragma unroll
  for (int f = 0; f < 4; ++f) {
    int ra = wm * 64 + f * 16 + r16;
    offA[f] = ra * 64 + ((g ^ ((ra >> 1) & 3)) << 4);
    int rb = wn * 64 + f * 16 + r16;
    offB[f] = rb * 64 + ((g ^ ((rb >> 1) & 3)) << 4);
  }

  auto stage_tile = [&](int ts) {
    char* base = smem + (ts & 1) * 32768;
    const u16* At = A + (size_t)ts * 64;
    const u16* Bt = B + (size_t)ts * 64;
#pragma unroll
    for (int l = 0; l < 4; ++l) {
      int i = l * 256 + tid;
      int ks = i >> 9, rem = i & 511, row = rem >> 2, x = rem & 3;
      int c = x ^ ((row >> 1) & 3);
      gld_lds16(At + (size_t)(m0 + row) * K + ks * 32 + c * 8,
                base + ks * 8192 + rem * 16);
    }
#pragma unroll
    for (int l = 0; l < 4; ++l) {
      int i = l * 256 + tid;
      int ks = i >> 9, rem = i & 511, row = rem >> 2, x = rem & 3;
      int c = x ^ ((row >> 1) & 3);
      gld_lds16(Bt + (size_t)(n0 + row) * K + ks * 32 + c * 8,
                base + 16384 + ks * 8192 + rem * 16);
    }
  };

  f32x4 acc[4][4];
#pragma unroll
  for (int i = 0; i < 4; ++i)
#pragma unroll
    for (int j = 0; j < 4; ++j) acc[i][j] = 0.0f;

  stage_tile(0);
  stage_tile(1);
  asm volatile("s_waitcnt vmcnt(8)" ::: "memory");
  __builtin_amdgcn_s_barrier();

  for (int t = 0; t < NT; ++t) {
    const char* Ab = smem + (t & 1) * 32768;
    const char* Bb = Ab + 16384;
#pragma unroll
    for (int ks = 0; ks < 2; ++ks) {
      bf16x8 ar[4], br[4];
#pragma unroll
      for (int f = 0; f < 4; ++f) ar[f] = *(const bf16x8*)(Ab + ks * 8192 + offA[f]);
#pragma unroll
      for (int f = 0; f < 4; ++f) br[f] = *(const bf16x8*)(Bb + ks * 8192 + offB[f]);
      __builtin_amdgcn_s_setprio(1);
#pragma unroll
      for (int mf = 0; mf < 4; ++mf)
#pragma unroll
        for (int nf = 0; nf < 4; ++nf)
          acc[mf][nf] = __builtin_amdgcn_mfma_f32_16x16x32_bf16(ar[mf], br[nf], acc[mf][nf], 0, 0, 0);
      __builtin_amdgcn_s_setprio(0);
    }
    asm volatile("s_waitcnt lgkmcnt(0)" ::: "memory");
    __builtin_amdgcn_s_barrier();
    if (t + 2 < NT) {
      stage_tile(t + 2);
      asm volatile("s_waitcnt vmcnt(8)" ::: "memory");
    } else {
      asm volatile("s_waitcnt vmcnt(0)" ::: "memory");
    }
    __builtin_amdgcn_s_barrier();
  }

  // ---------------- epilogues ----------------
  if constexpr (EPI == 0 || EPI == 1) {
    u8* C = (u8*)Cv;
#pragma unroll
    for (int mf = 0; mf < 4; ++mf)
#pragma unroll
      for (int nf = 0; nf < 4; ++nf)
#pragma unroll
        for (int r = 0; r < 4; ++r) {
          int gm = m0 + wm * 64 + mf * 16 + (g << 2) + r;
          int gn = n0 + wn * 64 + nf * 16 + r16;
          float val = acc[mf][nf][r] + bias[gn];
          int b = gm >> 9, s = gm & 511, hh = gn >> 9, d2 = gn & 511;
          if constexpr (EPI == 0)
            C[(size_t)b * 2097152 + (size_t)((s << 3) + hh) * 512 + d2] = f2fp8(val);
          else
            C[(size_t)b * 2097152 + (size_t)((hh << 9) + s) * 512 + d2] = f2fp8(val);
        }
  } else if constexpr (EPI == 2) {
    u16* E = (u16*)smem;   // 128 x 129
#pragma unroll
    for (int mf = 0; mf < 4; ++mf)
#pragma unroll
      for (int nf = 0; nf < 4; ++nf)
#pragma unroll
        for (int r = 0; r < 4; ++r) {
          int lm = wm * 64 + mf * 16 + (g << 2) + r;
          int ln = wn * 64 + nf * 16 + r16;
          E[lm * 129 + ln] = f2bf(acc[mf][nf][r] + bias[n0 + ln]);
        }
    __syncthreads();
    int b = m0 >> 9, s0 = m0 & 511, hh = n0 >> 9, d20 = n0 & 511;
    u16* C = (u16*)Cv;
    int c = tid >> 1;            // local col (d2), 128 cols, 2 thr/col
    int r0 = (tid & 1) * 64;     // half of 128 rows (s)
    u16* dst = C + (size_t)b * 2097152 + (size_t)(d20 + c) * 4096 + (hh << 9) + s0 + r0;
#pragma unroll
    for (int i = 0; i < 64; i += 8) {
      u16x8 p;
#pragma unroll
      for (int jj = 0; jj < 8; ++jj) p[jj] = E[(r0 + i + jj) * 129 + c];
      *(u16x8*)(dst + i) = p;
    }
  } else {  // EPI 7: PV / L -> oflat
    u16* C = (u16*)Cv + (size_t)z * bsC;
    const float* Lp = Lbuf + (size_t)z * 4096;
#pragma unroll
    for (int mf = 0; mf < 4; ++mf) {
#pragma unroll
      for (int r = 0; r < 4; ++r) {
        int gm = m0 + wm * 64 + mf * 16 + (g << 2) + r;
        float inv = 1.0f / Lp[gm];
#pragma unroll
        for (int nf = 0; nf < 4; ++nf) {
          int gn = n0 + wn * 64 + nf * 16 + r16;
          C[(size_t)(gm >> 3) * 4096 + (size_t)(gm & 7) * 512 + gn] =
              f2bf(acc[mf][nf][r] * inv);
        }
      }
    }
  }
}

// =====================================================================
// fp8 scores GEMM: P = exp(scale * (qp . kp)) bf16 + row-sum L (atomic).
// 128x128 tile, 256 thr, 2x2 waves, K-tile 64. LDS 32KB -> 4 blocks/CU.
// Swizzle: 8B slot s of (row,g): s = g ^ (2*((row>>2)&1)) (pair-preserving).
// =====================================================================
__global__ __launch_bounds__(256, 4) void gemm_f8(
    const u8* __restrict__ A, const u8* __restrict__ B, u16* __restrict__ C,
    float* __restrict__ Lbuf, int N, int K, float scale,
    long bsA, long bsB, long bsC)
{
  __shared__ alignas(16) char smem[32768];

  const int tid = threadIdx.x, lid = tid & 63, wid = tid >> 6;
  const int wm = wid >> 1, wn = wid & 1;
  const int g = lid >> 4, r16 = lid & 15;

  const int nx = gridDim.x, ny = gridDim.y;
  const int lin = blockIdx.x + nx * (blockIdx.y + ny * blockIdx.z);
  const int xcd = lin & 7, slot = lin >> 3;
  const int wx = slot % nx;
  const int c_ = xcd + (slot / nx) * 8;
  const int m0 = (c_ % ny) * 128, n0 = wx * 128, z = c_ / ny;

  A += (size_t)z * bsA;
  B += (size_t)z * bsB;
  const int NT = K >> 6;

  // frag byte offsets within a ks-half (4KB): row*32 + (g ^ 2*((row>>2)&1))*8
  int offA[4], offB[4];
#pragma unroll
  for (int f = 0; f < 4; ++f) {
    int ra = wm * 64 + f * 16 + r16;
    offA[f] = ra * 32 + ((g ^ (((ra >> 2) & 1) << 1)) << 3);
    int rb = wn * 64 + f * 16 + r16;
    offB[f] = rb * 32 + ((g ^ (((rb >> 2) & 1) << 1)) << 3);
  }

  auto stage_tile = [&](int ts) {
    char* base = smem + (ts & 1) * 16384;
    const u8* At = A + (size_t)ts * 64;
    const u8* Bt = B + (size_t)ts * 64;
#pragma unroll
    for (int l = 0; l < 2; ++l) {
      int i = l * 256 + tid;
      int ks = i >> 8, rem = i & 255, row = rem >> 1, p = rem & 1;
      int cp = p ^ ((row >> 2) & 1);
      gld_lds16(At + (size_t)(m0 + row) * K + ks * 32 + cp * 16,
                base + ks * 4096 + rem * 16);
    }
#pragma unroll
    for (int l = 0; l < 2; ++l) {
      int i = l * 256 + tid;
      int ks = i >> 8, rem = i & 255, row = rem >> 1, p = rem & 1;
      int cp = p ^ ((row >> 2) & 1);
      gld_lds16(Bt + (size_t)(n0 + row) * K + ks * 32 + cp * 16,
                base + 8192 + ks * 4096 + rem * 16);
    }
  };

  f32x4 acc[4][4];
#pragma unroll
  for (int i = 0; i < 4; ++i)
#pragma unroll
    for (int j = 0; j < 4; ++j) acc[i][j] = 0.0f;

  stage_tile(0);
  stage_tile(1);
  asm volatile("s_waitcnt vmcnt(4)" ::: "memory");
  __builtin_amdgcn_s_barrier();

  for (int t = 0; t < NT; ++t) {
    const char* Ab = smem + (t & 1) * 16384;
    const char* Bb = Ab + 8192;
#pragma unroll
    for (int ks = 0; ks < 2; ++ks) {
      long ar[4], br[4];
#pragma unroll
      for (int f = 0; f < 4; ++f) ar[f] = *(const long*)(Ab + ks * 4096 + offA[f]);
#pragma unroll
      for (int f = 0; f < 4; ++f) br[f] = *(const long*)(Bb + ks * 4096 + offB[f]);
      __builtin_amdgcn_s_setprio(1);
#pragma unroll
      for (int mf = 0; mf < 4; ++mf)
#pragma unroll
        for (int nf = 0; nf < 4; ++nf)
          acc[mf][nf] = __builtin_amdgcn_mfma_f32_16x16x32_fp8_fp8(ar[mf], br[nf], acc[mf][nf], 0, 0, 0);
      __builtin_amdgcn_s_setprio(0);
    }
    asm volatile("s_waitcnt lgkmcnt(0)" ::: "memory");
    __builtin_amdgcn_s_barrier();
    if (t + 2 < NT) {
      stage_tile(t + 2);
      asm volatile("s_waitcnt vmcnt(4)" ::: "memory");
    } else {
      asm volatile("s_waitcnt vmcnt(0)" ::: "memory");
    }
    __builtin_amdgcn_s_barrier();
  }

  // epilogue: P = exp(s*scale) bf16 + row-sum via shfl + atomicAdd
  u16* Cp = C + (size_t)z * bsC;
  float* Lp = Lbuf + (size_t)z * 4096;
#pragma unroll
  for (int mf = 0; mf < 4; ++mf) {
#pragma unroll
    for (int r = 0; r < 4; ++r) {
      int gm = m0 + wm * 64 + mf * 16 + (g << 2) + r;
      float rs = 0.0f;
#pragma unroll
      for (int nf = 0; nf < 4; ++nf) {
        int gn = n0 + wn * 64 + nf * 16 + r16;
        float p = __expf(acc[mf][nf][r] * scale);
        u16 pb = f2bf(p);
        rs += bf2f(pb);                 // sum exactly what PV consumes
        Cp[(size_t)gm * N + gn] = pb;
      }
      rs += __shfl_xor(rs, 1); rs += __shfl_xor(rs, 2);
      rs += __shfl_xor(rs, 4); rs += __shfl_xor(rs, 8);
      if (r16 == 0) atomicAdd(&Lp[gm], rs);
    }
  }
}

// ---------------- final projection, bf16 in, f32+bias out, 64x64 tile ----------------
__global__ __launch_bounds__(256) void gemm_bt_final(
    const u16* __restrict__ A, const u16* __restrict__ B, float* __restrict__ C,
    const float* __restrict__ bias, int N, int K)
{
  constexpr int BM = 64, BN = 64, BK = 64;
  __shared__ alignas(16) char smem[(BM + BN) * BK * 2];
  u16* As = (u16*)smem;
  u16* Bs = As + BM * BK;

  const int tid = threadIdx.x;
  const int lid = tid & 63, wid = tid >> 6;
  const int m0 = blockIdx.y * BM, n0 = blockIdx.x * BN;
  const int wm = wid >> 1, wn = wid & 1;

  f32x4 acc[2][2];
#pragma unroll
  for (int i = 0; i < 2; ++i)
#pragma unroll
    for (int j = 0; j < 2; ++j) acc[i][j] = 0.0f;

  const int rA = lid >> 3;
  const int ke = (lid & 7) * 8;

  const int nK = K / BK;
  for (int kt = 0; kt < nK; ++kt) {
    const int k0 = kt * BK;
#pragma unroll
    for (int c = 0; c < 2; ++c) {
      int chunk = wid * 2 + c;
      gld_lds16(A + (size_t)(m0 + chunk * 8 + rA) * K + k0 + ke, (char*)As + chunk * 1024);
    }
#pragma unroll
    for (int c = 0; c < 2; ++c) {
      int chunk = wid * 2 + c;
      gld_lds16(B + (size_t)(n0 + chunk * 8 + rA) * K + k0 + ke, (char*)Bs + chunk * 1024);
    }
    __syncthreads();
#pragma unroll
    for (int kc = 0; kc < 2; ++kc) {
      bf16x8 af[2], bfv[2];
      const int kb = kc * 32 + (lid >> 4) * 8;
#pragma unroll
      for (int i = 0; i < 2; ++i)
        af[i] = *(const bf16x8*)&As[(wm * 32 + i * 16 + (lid & 15)) * BK + kb];
#pragma unroll
      for (int j = 0; j < 2; ++j)
        bfv[j] = *(const bf16x8*)&Bs[(wn * 32 + j * 16 + (lid & 15)) * BK + kb];
#pragma unroll
      for (int i = 0; i < 2; ++i)
#pragma unroll
        for (int j = 0; j < 2; ++j)
          acc[i][j] = __builtin_amdgcn_mfma_f32_16x16x32_bf16(af[i], bfv[j], acc[i][j], 0, 0, 0);
    }
    __syncthreads();
  }

#pragma unroll
  for (int i = 0; i < 2; ++i)
#pragma unroll
    for (int j = 0; j < 2; ++j)
#pragma unroll
      for (int r = 0; r < 4; ++r) {
        int gm = m0 + wm * 32 + i * 16 + ((lid >> 4) << 2) + r;
        int gn = n0 + wn * 32 + j * 16 + (lid & 15);
        C[(size_t)gm * N + gn] = acc[i][j][r] + bias[gn];
      }
}

// ---------------------------------------------------------------------------
extern "C" void kernel_launch(void* const* d_in, const int* in_sizes, int n_in,
                              void* d_out, int out_size, void* d_ws, size_t ws_size,
                              hipStream_t stream) {
  (void)in_sizes; (void)n_in; (void)out_size; (void)ws_size;
  const float* q_f  = (const float*)d_in[0];
  const float* k_f  = (const float*)d_in[1];
  const float* v_f  = (const float*)d_in[2];
  const float* wq_b = (const float*)d_in[4];
  const float* wk_b = (const float*)d_in[6];
  const float* wv_b = (const float*)d_in[8];
  const float* ou_b = (const float*)d_in[10];
  float* out = (float*)d_out;

  char* ws = (char*)d_ws;
  u16* q_bf  = (u16*)(ws + 0);          // 2MB  bf16(q)
  u16* k_bf  = (u16*)(ws + 2097152);    // 2MB
  u16* v_bf  = (u16*)(ws + 4194304);    // 2MB
  u16* wA_q  = (u16*)(ws + 6291456);    // 4MB  bf16(wk_w) (reference swap)
  u16* wA_k  = (u16*)(ws + 10485760);   // 4MB  bf16(wq_w)
  u16* wA_v  = (u16*)(ws + 14680064);   // 4MB  bf16(wv_w)
  u16* ow_bf = (u16*)(ws + 18874368);   // 4MB  bf16(out_w)
  u8*  qp    = (u8*)(ws + 23068672);    // 8MB  (4,4096,512) fp8, l = s*8+h
  u8*  kp    = (u8*)(ws + 31457280);    // 8MB  (4,4096,512) fp8, l' = h*512+s
  u16* vpt   = (u16*)(ws + 39845888);   // 16MB (4,512,4096) bf16, [d2][l']
  u16* oflat = (u16*)(ws + 56623104);   // 16MB (4,512,4096) bf16
  u16* P     = (u16*)(ws + 73400320);   // 128MB (4,4096,4096) bf16

  float* L = (float*)d_out;  // 64KB row-sums; dead until final GEMM overwrites

  // converts (all bf16)
  cvt_kernel<<<512,  256, 0, stream>>>(q_f, q_bf, 1048576);
  cvt_kernel<<<512,  256, 0, stream>>>(k_f, k_bf, 1048576);
  cvt_kernel<<<512,  256, 0, stream>>>(v_f, v_bf, 1048576);
  cvt_kernel<<<1024, 256, 0, stream>>>((const float*)d_in[5], wA_q, 2097152);
  cvt_kernel<<<1024, 256, 0, stream>>>((const float*)d_in[3], wA_k, 2097152);
  cvt_kernel<<<1024, 256, 0, stream>>>((const float*)d_in[7], wA_v, 2097152);
  cvt_kernel<<<1024, 256, 0, stream>>>((const float*)d_in[9], ow_bf, 2097152);

  // projections in bf16; qp/kp stored fp8, vpt stored bf16 (reference swap: qp uses wk, kp uses wq)
  gemm_bf<0><<<dim3(32,16,1), 256, 0, stream>>>(q_bf, wA_q, qp,  wk_b, nullptr, 4096, 512, 0,0,0);
  gemm_bf<1><<<dim3(32,16,1), 256, 0, stream>>>(k_bf, wA_k, kp,  wq_b, nullptr, 4096, 512, 0,0,0);
  gemm_bf<2><<<dim3(32,16,1), 256, 0, stream>>>(v_bf, wA_v, vpt, wv_b, nullptr, 4096, 512, 0,0,0);

  const float scl = 0.04419417382415922f;  // 1/sqrt(512)
  hipMemsetAsync(L, 0, 65536, stream);
  // scores: P = exp(s*scl) bf16 + row-sums into L   (fp8 operands)
  gemm_f8<<<dim3(32,32,4), 256, 0, stream>>>(qp, kp, P, L, 4096, 512, scl,
                                             2097152, 2097152, 16777216);
  // PV: O = (P @ V) / L -> oflat bf16   (bf16 operands)
  gemm_bf<7><<<dim3(4,32,4), 256, 0, stream>>>(P, vpt, oflat, nullptr, L, 512, 4096,
                                               16777216, 2097152, 2097152);
  // final projection, bf16 -> f32 + bias
  gemm_bt_final<<<dim3(8,32,1), 256, 0, stream>>>(oflat, ow_bf, out, ou_b, 512, 4096);
}

// Round 7
// 245.715 us; speedup vs baseline: 1.4430x; 1.1692x over previous
//
#include <hip/hip_runtime.h>
#include <cstddef>

typedef unsigned short u16;
typedef unsigned char u8;
typedef unsigned u32;
typedef float f32x4 __attribute__((ext_vector_type(4)));
typedef u16 u16x8 __attribute__((ext_vector_type(8)));
typedef u8 u8x8 __attribute__((ext_vector_type(8)));
typedef __bf16 bf16x8 __attribute__((ext_vector_type(8)));
typedef long lx2 __attribute__((ext_vector_type(2)));

__device__ __forceinline__ u16 f2bf(float f) {
  u32 u = __builtin_bit_cast(u32, f);
  u += 0x7fffu + ((u >> 16) & 1u);   // RTNE
  return (u16)(u >> 16);
}
__device__ __forceinline__ float bf2f(u16 h) {
  return __builtin_bit_cast(float, ((u32)h) << 16);
}
__device__ __forceinline__ u8 f2fp8(float v) {
  int t = __builtin_amdgcn_cvt_pk_fp8_f32(v, v, 0, false);
  return (u8)(t & 0xff);
}
__device__ __forceinline__ void gld_lds16(const void* g, void* l) {
  __builtin_amdgcn_global_load_lds((const __attribute__((address_space(1))) void*)g,
                                   (__attribute__((address_space(3))) void*)l, 16, 0, 0);
}

// ---------------- f32 -> bf16, 8 elems/thread ----------------
__global__ __launch_bounds__(256) void cvt_kernel(const float* __restrict__ in,
                                                  u16* __restrict__ out, int n) {
  int i = (blockIdx.x * 256 + threadIdx.x) * 8;
  if (i >= n) return;
  f32x4 a = *(const f32x4*)(in + i);
  f32x4 b = *(const f32x4*)(in + i + 4);
  u16x8 o;
  o[0] = f2bf(a[0]); o[1] = f2bf(a[1]); o[2] = f2bf(a[2]); o[3] = f2bf(a[3]);
  o[4] = f2bf(b[0]); o[5] = f2bf(b[1]); o[6] = f2bf(b[2]); o[7] = f2bf(b[3]);
  *(u16x8*)(out + i) = o;
}

// =====================================================================
// bf16 pipelined 128x128 B^T GEMM (projections).  256 thr, 4 waves.
// EPI: 0 qp-proj -> fp8   1 kp-proj -> fp8
//      2 vpt-proj -> fp8 transposed + kv-interleave permuted
// =====================================================================
template<int EPI>
__global__ __launch_bounds__(256, 2) void gemm_bf(
    const u16* __restrict__ A, const u16* __restrict__ B, void* __restrict__ Cv,
    const float* __restrict__ bias, int N, int K)
{
  __shared__ alignas(16) char smem[65536];

  const int tid = threadIdx.x, lid = tid & 63, wid = tid >> 6;
  const int wm = wid >> 1, wn = wid & 1;
  const int g = lid >> 4, r16 = lid & 15;

  const int nx = gridDim.x, ny = gridDim.y;
  const int lin = blockIdx.x + nx * blockIdx.y;
  const int xcd = lin & 7, slot = lin >> 3;
  const int wx = slot % nx;
  const int c_ = xcd + (slot / nx) * 8;
  const int m0 = (c_ % ny) * 128, n0 = wx * 128;

  const int NT = K >> 6;

  int offA[4], offB[4];
#pragma unroll
  for (int f = 0; f < 4; ++f) {
    int ra = wm * 64 + f * 16 + r16;
    offA[f] = ra * 64 + ((g ^ ((ra >> 1) & 3)) << 4);
    int rb = wn * 64 + f * 16 + r16;
    offB[f] = rb * 64 + ((g ^ ((rb >> 1) & 3)) << 4);
  }

  auto stage_tile = [&](int ts) {
    char* base = smem + (ts & 1) * 32768;
    const u16* At = A + (size_t)ts * 64;
    const u16* Bt = B + (size_t)ts * 64;
#pragma unroll
    for (int l = 0; l < 4; ++l) {
      int i = l * 256 + tid;
      int ks = i >> 9, rem = i & 511, row = rem >> 2, x = rem & 3;
      int c = x ^ ((row >> 1) & 3);
      gld_lds16(At + (size_t)(m0 + row) * K + ks * 32 + c * 8,
                base + ks * 8192 + rem * 16);
    }
#pragma unroll
    for (int l = 0; l < 4; ++l) {
      int i = l * 256 + tid;
      int ks = i >> 9, rem = i & 511, row = rem >> 2, x = rem & 3;
      int c = x ^ ((row >> 1) & 3);
      gld_lds16(Bt + (size_t)(n0 + row) * K + ks * 32 + c * 8,
                base + 16384 + ks * 8192 + rem * 16);
    }
  };

  f32x4 acc[4][4];
#pragma unroll
  for (int i = 0; i < 4; ++i)
#pragma unroll
    for (int j = 0; j < 4; ++j) acc[i][j] = 0.0f;

  stage_tile(0);
  stage_tile(1);
  asm volatile("s_waitcnt vmcnt(8)" ::: "memory");
  __builtin_amdgcn_s_barrier();

  for (int t = 0; t < NT; ++t) {
    const char* Ab = smem + (t & 1) * 32768;
    const char* Bb = Ab + 16384;
#pragma unroll
    for (int ks = 0; ks < 2; ++ks) {
      bf16x8 ar[4], br[4];
#pragma unroll
      for (int f = 0; f < 4; ++f) ar[f] = *(const bf16x8*)(Ab + ks * 8192 + offA[f]);
#pragma unroll
      for (int f = 0; f < 4; ++f) br[f] = *(const bf16x8*)(Bb + ks * 8192 + offB[f]);
      __builtin_amdgcn_s_setprio(1);
#pragma unroll
      for (int mf = 0; mf < 4; ++mf)
#pragma unroll
        for (int nf = 0; nf < 4; ++nf)
          acc[mf][nf] = __builtin_amdgcn_mfma_f32_16x16x32_bf16(ar[mf], br[nf], acc[mf][nf], 0, 0, 0);
      __builtin_amdgcn_s_setprio(0);
    }
    asm volatile("s_waitcnt lgkmcnt(0)" ::: "memory");
    __builtin_amdgcn_s_barrier();
    if (t + 2 < NT) {
      stage_tile(t + 2);
      asm volatile("s_waitcnt vmcnt(8)" ::: "memory");
    } else {
      asm volatile("s_waitcnt vmcnt(0)" ::: "memory");
    }
    __builtin_amdgcn_s_barrier();
  }

  // ---------------- epilogues ----------------
  if constexpr (EPI == 0 || EPI == 1) {
    u8* C = (u8*)Cv;
#pragma unroll
    for (int mf = 0; mf < 4; ++mf)
#pragma unroll
      for (int nf = 0; nf < 4; ++nf)
#pragma unroll
        for (int r = 0; r < 4; ++r) {
          int gm = m0 + wm * 64 + mf * 16 + (g << 2) + r;
          int gn = n0 + wn * 64 + nf * 16 + r16;
          float val = acc[mf][nf][r] + bias[gn];
          int b = gm >> 9, s = gm & 511, hh = gn >> 9, d2 = gn & 511;
          if constexpr (EPI == 0)
            C[(size_t)b * 2097152 + (size_t)((s << 3) + hh) * 512 + d2] = f2fp8(val);
          else
            C[(size_t)b * 2097152 + (size_t)((hh << 9) + s) * 512 + d2] = f2fp8(val);
        }
  } else {  // EPI == 2: vpt fp8, transposed, kv-permuted (pos t holds kv=(t&3)*16+(t>>2))
    u16* E = (u16*)smem;   // 128 x 129 bf16
#pragma unroll
    for (int mf = 0; mf < 4; ++mf)
#pragma unroll
      for (int nf = 0; nf < 4; ++nf)
#pragma unroll
        for (int r = 0; r < 4; ++r) {
          int lm = wm * 64 + mf * 16 + (g << 2) + r;
          int ln = wn * 64 + nf * 16 + r16;
          E[lm * 129 + ln] = f2bf(acc[mf][nf][r] + bias[n0 + ln]);
        }
    __syncthreads();
    int b = m0 >> 9, s0 = m0 & 511, hh = n0 >> 9, d20 = n0 & 511;
    u8* C = (u8*)Cv;
    int c = tid >> 1;            // local col (d2), 128 cols, 2 thr/col
    int r0 = (tid & 1) * 64;     // which 64-block of the 128 rows (s)
    u8* dst = C + (size_t)b * 2097152 + (size_t)(d20 + c) * 4096 + (hh << 9) + s0 + r0;
#pragma unroll
    for (int i = 0; i < 64; i += 8) {
      u8x8 p;
#pragma unroll
      for (int jj = 0; jj < 8; ++jj) {
        int t = i + jj;
        int sl = r0 + ((t & 3) << 4) + (t >> 2);   // kv of out-position t
        p[jj] = f2fp8(bf2f(E[sl * 129 + c]));
      }
      *(u8x8*)(dst + i) = p;
    }
  }
}

// =====================================================================
// fp8 pipelined 128x128 B^T GEMM (scores / PV). 256 thr, 4 waves (2Mx2N).
// K-tile = 64 bytes/row; LDS 2 bufs x (A 8KB + B 8KB) = 32KB -> 4 blk/CU.
// b128 frag reads: one 16B read = both K-halves (virtual-k reorder, A/B
// consistent). Swizzle: 16B slot x = g ^ ((row>>1)&3)  (2-way max = free).
// EPI: 6 scores  P(u8, kv-permuted packed u32) = exp(s*scale), rowsum L
//      7 PV      O = (P@V)/L -> oflat bf16
// =====================================================================
template<int EPI>
__global__ __launch_bounds__(256, 4) void gemm_f8(
    const u8* __restrict__ A, const u8* __restrict__ B, void* __restrict__ Cv,
    float* __restrict__ Lbuf, int N, int K, float scale,
    long bsA, long bsB, long bsC)
{
  __shared__ alignas(16) char smem[32768];

  const int tid = threadIdx.x, lid = tid & 63, wid = tid >> 6;
  const int wm = wid >> 1, wn = wid & 1;
  const int g = lid >> 4, r16 = lid & 15;

  const int nx = gridDim.x, ny = gridDim.y;
  const int lin = blockIdx.x + nx * (blockIdx.y + ny * blockIdx.z);
  const int xcd = lin & 7, slot = lin >> 3;
  const int wx = slot % nx;
  const int c_ = xcd + (slot / nx) * 8;
  const int m0 = (c_ % ny) * 128, n0 = wx * 128, z = c_ / ny;

  A += (size_t)z * bsA;
  B += (size_t)z * bsB;
  const int NT = K >> 6;

  int offA[4], offB[4];
#pragma unroll
  for (int f = 0; f < 4; ++f) {
    int ra = wm * 64 + f * 16 + r16;
    offA[f] = ra * 64 + ((g ^ ((ra >> 1) & 3)) << 4);
    int rb = wn * 64 + f * 16 + r16;
    offB[f] = rb * 64 + ((g ^ ((rb >> 1) & 3)) << 4);
  }

  auto stage_tile = [&](int ts) {
    char* base = smem + (ts & 1) * 16384;
    const u8* At = A + (size_t)ts * 64;
    const u8* Bt = B + (size_t)ts * 64;
#pragma unroll
    for (int l = 0; l < 2; ++l) {
      int i = l * 256 + tid;
      int row = i >> 2, x = i & 3;
      int c = x ^ ((row >> 1) & 3);
      gld_lds16(At + (size_t)(m0 + row) * K + c * 16, base + i * 16);
    }
#pragma unroll
    for (int l = 0; l < 2; ++l) {
      int i = l * 256 + tid;
      int row = i >> 2, x = i & 3;
      int c = x ^ ((row >> 1) & 3);
      gld_lds16(Bt + (size_t)(n0 + row) * K + c * 16, base + 8192 + i * 16);
    }
  };

  f32x4 acc[4][4];
#pragma unroll
  for (int i = 0; i < 4; ++i)
#pragma unroll
    for (int j = 0; j < 4; ++j) acc[i][j] = 0.0f;

  stage_tile(0);
  stage_tile(1);
  asm volatile("s_waitcnt vmcnt(4)" ::: "memory");
  __builtin_amdgcn_s_barrier();

  for (int t = 0; t < NT; ++t) {
    const char* Ab = smem + (t & 1) * 16384;
    const char* Bb = Ab + 8192;
    lx2 ar[4], br[4];
#pragma unroll
    for (int f = 0; f < 4; ++f) ar[f] = *(const lx2*)(Ab + offA[f]);
#pragma unroll
    for (int f = 0; f < 4; ++f) br[f] = *(const lx2*)(Bb + offB[f]);
    __builtin_amdgcn_s_setprio(1);
#pragma unroll
    for (int mf = 0; mf < 4; ++mf)
#pragma unroll
      for (int nf = 0; nf < 4; ++nf) {
        acc[mf][nf] = __builtin_amdgcn_mfma_f32_16x16x32_fp8_fp8(ar[mf][0], br[nf][0], acc[mf][nf], 0, 0, 0);
        acc[mf][nf] = __builtin_amdgcn_mfma_f32_16x16x32_fp8_fp8(ar[mf][1], br[nf][1], acc[mf][nf], 0, 0, 0);
      }
    __builtin_amdgcn_s_setprio(0);
    asm volatile("s_waitcnt lgkmcnt(0)" ::: "memory");
    __builtin_amdgcn_s_barrier();
    if (t + 2 < NT) {
      stage_tile(t + 2);
      asm volatile("s_waitcnt vmcnt(4)" ::: "memory");
    } else {
      asm volatile("s_waitcnt vmcnt(0)" ::: "memory");
    }
    __builtin_amdgcn_s_barrier();
  }

  if constexpr (EPI == 6) {
    // P = exp(s*scale) -> fp8, kv-permuted packed u32; rowsum L via shfl+atomic
    u8* Cp = (u8*)Cv + (size_t)z * bsC;
    float* Lp = Lbuf + (size_t)z * 4096;
#pragma unroll
    for (int mf = 0; mf < 4; ++mf) {
#pragma unroll
      for (int r = 0; r < 4; ++r) {
        int gm = m0 + wm * 64 + mf * 16 + (g << 2) + r;
        float p0 = __expf(acc[mf][0][r] * scale);
        float p1 = __expf(acc[mf][1][r] * scale);
        float p2 = __expf(acc[mf][2][r] * scale);
        float p3 = __expf(acc[mf][3][r] * scale);
        float rs = (p0 + p1) + (p2 + p3);
        int pk = __builtin_amdgcn_cvt_pk_fp8_f32(p0, p1, 0, false);
        pk = __builtin_amdgcn_cvt_pk_fp8_f32(p2, p3, pk, true);
        *(u32*)(Cp + (size_t)gm * N + n0 + wn * 64 + r16 * 4) = (u32)pk;
        rs += __shfl_xor(rs, 1); rs += __shfl_xor(rs, 2);
        rs += __shfl_xor(rs, 4); rs += __shfl_xor(rs, 8);
        if (r16 == 0) atomicAdd(&Lp[gm], rs);
      }
    }
  } else {
    // PV: O = acc / L[row] -> oflat bf16
    u16* C = (u16*)Cv + (size_t)z * bsC;
    const float* Lp = Lbuf + (size_t)z * 4096;
#pragma unroll
    for (int mf = 0; mf < 4; ++mf) {
#pragma unroll
      for (int r = 0; r < 4; ++r) {
        int gm = m0 + wm * 64 + mf * 16 + (g << 2) + r;
        float inv = 1.0f / Lp[gm];
#pragma unroll
        for (int nf = 0; nf < 4; ++nf) {
          int gn = n0 + wn * 64 + nf * 16 + r16;
          C[(size_t)(gm >> 3) * 4096 + (size_t)(gm & 7) * 512 + gn] =
              f2bf(acc[mf][nf][r] * inv);
        }
      }
    }
  }
}

// ---------------- final projection, bf16 in, f32+bias out, 64x64 tile ----------------
__global__ __launch_bounds__(256) void gemm_bt_final(
    const u16* __restrict__ A, const u16* __restrict__ B, float* __restrict__ C,
    const float* __restrict__ bias, int N, int K)
{
  constexpr int BM = 64, BN = 64, BK = 64;
  __shared__ alignas(16) char smem[(BM + BN) * BK * 2];
  u16* As = (u16*)smem;
  u16* Bs = As + BM * BK;

  const int tid = threadIdx.x;
  const int lid = tid & 63, wid = tid >> 6;
  const int m0 = blockIdx.y * BM, n0 = blockIdx.x * BN;
  const int wm = wid >> 1, wn = wid & 1;

  f32x4 acc[2][2];
#pragma unroll
  for (int i = 0; i < 2; ++i)
#pragma unroll
    for (int j = 0; j < 2; ++j) acc[i][j] = 0.0f;

  const int rA = lid >> 3;
  const int ke = (lid & 7) * 8;

  const int nK = K / BK;
  for (int kt = 0; kt < nK; ++kt) {
    const int k0 = kt * BK;
#pragma unroll
    for (int c = 0; c < 2; ++c) {
      int chunk = wid * 2 + c;
      gld_lds16(A + (size_t)(m0 + chunk * 8 + rA) * K + k0 + ke, (char*)As + chunk * 1024);
    }
#pragma unroll
    for (int c = 0; c < 2; ++c) {
      int chunk = wid * 2 + c;
      gld_lds16(B + (size_t)(n0 + chunk * 8 + rA) * K + k0 + ke, (char*)Bs + chunk * 1024);
    }
    __syncthreads();
#pragma unroll
    for (int kc = 0; kc < 2; ++kc) {
      bf16x8 af[2], bfv[2];
      const int kb = kc * 32 + (lid >> 4) * 8;
#pragma unroll
      for (int i = 0; i < 2; ++i)
        af[i] = *(const bf16x8*)&As[(wm * 32 + i * 16 + (lid & 15)) * BK + kb];
#pragma unroll
      for (int j = 0; j < 2; ++j)
        bfv[j] = *(const bf16x8*)&Bs[(wn * 32 + j * 16 + (lid & 15)) * BK + kb];
#pragma unroll
      for (int i = 0; i < 2; ++i)
#pragma unroll
        for (int j = 0; j < 2; ++j)
          acc[i][j] = __builtin_amdgcn_mfma_f32_16x16x32_bf16(af[i], bfv[j], acc[i][j], 0, 0, 0);
    }
    __syncthreads();
  }

#pragma unroll
  for (int i = 0; i < 2; ++i)
#pragma unroll
    for (int j = 0; j < 2; ++j)
#pragma unroll
      for (int r = 0; r < 4; ++r) {
        int gm = m0 + wm * 32 + i * 16 + ((lid >> 4) << 2) + r;
        int gn = n0 + wn * 32 + j * 16 + (lid & 15);
        C[(size_t)gm * N + gn] = acc[i][j][r] + bias[gn];
      }
}

// ---------------------------------------------------------------------------
extern "C" void kernel_launch(void* const* d_in, const int* in_sizes, int n_in,
                              void* d_out, int out_size, void* d_ws, size_t ws_size,
                              hipStream_t stream) {
  (void)in_sizes; (void)n_in; (void)out_size; (void)ws_size;
  const float* q_f  = (const float*)d_in[0];
  const float* k_f  = (const float*)d_in[1];
  const float* v_f  = (const float*)d_in[2];
  const float* wq_b = (const float*)d_in[4];
  const float* wk_b = (const float*)d_in[6];
  const float* wv_b = (const float*)d_in[8];
  const float* ou_b = (const float*)d_in[10];
  float* out = (float*)d_out;

  char* ws = (char*)d_ws;
  u16* q_bf  = (u16*)(ws + 0);          // 2MB  bf16(q)
  u16* k_bf  = (u16*)(ws + 2097152);    // 2MB
  u16* v_bf  = (u16*)(ws + 4194304);    // 2MB
  u16* wA_q  = (u16*)(ws + 6291456);    // 4MB  bf16(wk_w) (reference swap)
  u16* wA_k  = (u16*)(ws + 10485760);   // 4MB  bf16(wq_w)
  u16* wA_v  = (u16*)(ws + 14680064);   // 4MB  bf16(wv_w)
  u16* ow_bf = (u16*)(ws + 18874368);   // 4MB  bf16(out_w)
  u8*  qp    = (u8*)(ws + 23068672);    // 8MB  (4,4096,512) fp8, l = s*8+h
  u8*  kp    = (u8*)(ws + 31457280);    // 8MB  (4,4096,512) fp8, l' = h*512+s
  u8*  vpt   = (u8*)(ws + 39845888);    // 8MB  (4,512,4096) fp8, [d2][m'] kv-permuted
  u16* oflat = (u16*)(ws + 48234496);   // 16MB (4,512,4096) bf16
  u8*  P     = (u8*)(ws + 65011712);    // 64MB (4,4096,4096) fp8, cols kv-permuted

  float* L = (float*)d_out;  // 64KB row-sums; dead until final GEMM overwrites

  // converts (bf16 — projections must stay bf16 for accuracy)
  cvt_kernel<<<512,  256, 0, stream>>>(q_f, q_bf, 1048576);
  cvt_kernel<<<512,  256, 0, stream>>>(k_f, k_bf, 1048576);
  cvt_kernel<<<512,  256, 0, stream>>>(v_f, v_bf, 1048576);
  cvt_kernel<<<1024, 256, 0, stream>>>((const float*)d_in[5], wA_q, 2097152);
  cvt_kernel<<<1024, 256, 0, stream>>>((const float*)d_in[3], wA_k, 2097152);
  cvt_kernel<<<1024, 256, 0, stream>>>((const float*)d_in[7], wA_v, 2097152);
  cvt_kernel<<<1024, 256, 0, stream>>>((const float*)d_in[9], ow_bf, 2097152);

  // projections in bf16; qp/kp/vpt stored fp8 (reference swap: qp uses wk, kp uses wq)
  gemm_bf<0><<<dim3(32,16,1), 256, 0, stream>>>(q_bf, wA_q, qp,  wk_b, 4096, 512);
  gemm_bf<1><<<dim3(32,16,1), 256, 0, stream>>>(k_bf, wA_k, kp,  wq_b, 4096, 512);
  gemm_bf<2><<<dim3(32,16,1), 256, 0, stream>>>(v_bf, wA_v, vpt, wv_b, 4096, 512);

  const float scl = 0.04419417382415922f;  // 1/sqrt(512)
  hipMemsetAsync(L, 0, 65536, stream);
  // scores: P = exp(s*scl) fp8 (kv-permuted) + row-sums into L   (fp8 operands)
  gemm_f8<6><<<dim3(32,32,4), 256, 0, stream>>>(qp, kp, P, L, 4096, 512, scl,
                                                2097152, 2097152, 16777216);
  // PV: O = (P @ V) / L -> oflat bf16   (fp8 operands, matching kv permutation)
  gemm_f8<7><<<dim3(4,32,4), 256, 0, stream>>>(P, vpt, oflat, L, 512, 4096, 1.f,
                                               16777216, 2097152, 2097152);
  // final projection, bf16 -> f32 + bias
  gemm_bt_final<<<dim3(8,32,1), 256, 0, stream>>>(oflat, ow_bf, out, ou_b, 512, 4096);
}

// Round 8
// 243.090 us; speedup vs baseline: 1.4585x; 1.0108x over previous
//
#include <hip/hip_runtime.h>
#include <cstddef>

typedef unsigned short u16;
typedef unsigned char u8;
typedef unsigned u32;
typedef float f32x4 __attribute__((ext_vector_type(4)));
typedef u16 u16x4 __attribute__((ext_vector_type(4)));
typedef u16 u16x8 __attribute__((ext_vector_type(8)));
typedef u8 u8x8 __attribute__((ext_vector_type(8)));
typedef __bf16 bf16x8 __attribute__((ext_vector_type(8)));
typedef long lx2 __attribute__((ext_vector_type(2)));

__device__ __forceinline__ u16 f2bf(float f) {
  u32 u = __builtin_bit_cast(u32, f);
  u += 0x7fffu + ((u >> 16) & 1u);   // RTNE
  return (u16)(u >> 16);
}
__device__ __forceinline__ float bf2f(u16 h) {
  return __builtin_bit_cast(float, ((u32)h) << 16);
}
__device__ __forceinline__ u8 f2fp8(float v) {
  int t = __builtin_amdgcn_cvt_pk_fp8_f32(v, v, 0, false);
  return (u8)(t & 0xff);
}
__device__ __forceinline__ void gld_lds16(const void* g, void* l) {
  __builtin_amdgcn_global_load_lds((const __attribute__((address_space(1))) void*)g,
                                   (__attribute__((address_space(3))) void*)l, 16, 0, 0);
}

// ---------------- f32 -> bf16, 8 elems/thread ----------------
__global__ __launch_bounds__(256) void cvt_kernel(const float* __restrict__ in,
                                                  u16* __restrict__ out, int n) {
  int i = (blockIdx.x * 256 + threadIdx.x) * 8;
  if (i >= n) return;
  f32x4 a = *(const f32x4*)(in + i);
  f32x4 b = *(const f32x4*)(in + i + 4);
  u16x8 o;
  o[0] = f2bf(a[0]); o[1] = f2bf(a[1]); o[2] = f2bf(a[2]); o[3] = f2bf(a[3]);
  o[4] = f2bf(b[0]); o[5] = f2bf(b[1]); o[6] = f2bf(b[2]); o[7] = f2bf(b[3]);
  *(u16x8*)(out + i) = o;
}

// ---- f32 -> bf16 with within-64 K-group permutation (pos t <- true (t&3)*16+(t>>2)) ----
// Matches oflat's packed-store column permutation; rows x 4096 cols.
__global__ __launch_bounds__(256) void cvt_permK(const float* __restrict__ in,
                                                 u16* __restrict__ out, int n) {
  int i = (blockIdx.x * 256 + threadIdx.x) * 8;
  if (i >= n) return;
  int row = i >> 12, col0 = i & 4095;
  int group = col0 & ~63, t0 = col0 & 63;
  const float* rp = in + ((size_t)row << 12) + group;
  u16x8 o;
#pragma unroll
  for (int j = 0; j < 8; ++j) {
    int t = t0 + j;
    o[j] = f2bf(rp[((t & 3) << 4) + (t >> 2)]);
  }
  *(u16x8*)(out + i) = o;
}

// =====================================================================
// bf16 pipelined 128x128 B^T GEMM (projections).  256 thr, 4 waves.
// EPI: 0 qp-proj -> fp8 (d2 within-64 permuted, packed u32 stores)
//      1 kp-proj -> fp8 (same packing)
//      2 vpt-proj -> fp8 transposed + kv-interleave permuted
// =====================================================================
template<int EPI>
__global__ __launch_bounds__(256, 2) void gemm_bf(
    const u16* __restrict__ A, const u16* __restrict__ B, void* __restrict__ Cv,
    const float* __restrict__ bias, int N, int K)
{
  __shared__ alignas(16) char smem[65536];

  const int tid = threadIdx.x, lid = tid & 63, wid = tid >> 6;
  const int wm = wid >> 1, wn = wid & 1;
  const int g = lid >> 4, r16 = lid & 15;

  const int nx = gridDim.x, ny = gridDim.y;
  const int lin = blockIdx.x + nx * blockIdx.y;
  const int xcd = lin & 7, slot = lin >> 3;
  const int wx = slot % nx;
  const int c_ = xcd + (slot / nx) * 8;
  const int m0 = (c_ % ny) * 128, n0 = wx * 128;

  const int NT = K >> 6;

  int offA[4], offB[4];
#pragma unroll
  for (int f = 0; f < 4; ++f) {
    int ra = wm * 64 + f * 16 + r16;
    offA[f] = ra * 64 + ((g ^ ((ra >> 1) & 3)) << 4);
    int rb = wn * 64 + f * 16 + r16;
    offB[f] = rb * 64 + ((g ^ ((rb >> 1) & 3)) << 4);
  }

  auto stage_tile = [&](int ts) {
    char* base = smem + (ts & 1) * 32768;
    const u16* At = A + (size_t)ts * 64;
    const u16* Bt = B + (size_t)ts * 64;
#pragma unroll
    for (int l = 0; l < 4; ++l) {
      int i = l * 256 + tid;
      int ks = i >> 9, rem = i & 511, row = rem >> 2, x = rem & 3;
      int c = x ^ ((row >> 1) & 3);
      gld_lds16(At + (size_t)(m0 + row) * K + ks * 32 + c * 8,
                base + ks * 8192 + rem * 16);
    }
#pragma unroll
    for (int l = 0; l < 4; ++l) {
      int i = l * 256 + tid;
      int ks = i >> 9, rem = i & 511, row = rem >> 2, x = rem & 3;
      int c = x ^ ((row >> 1) & 3);
      gld_lds16(Bt + (size_t)(n0 + row) * K + ks * 32 + c * 8,
                base + 16384 + ks * 8192 + rem * 16);
    }
  };

  f32x4 acc[4][4];
#pragma unroll
  for (int i = 0; i < 4; ++i)
#pragma unroll
    for (int j = 0; j < 4; ++j) acc[i][j] = 0.0f;

  stage_tile(0);
  stage_tile(1);
  asm volatile("s_waitcnt vmcnt(8)" ::: "memory");
  __builtin_amdgcn_s_barrier();

  for (int t = 0; t < NT; ++t) {
    const char* Ab = smem + (t & 1) * 32768;
    const char* Bb = Ab + 16384;
#pragma unroll
    for (int ks = 0; ks < 2; ++ks) {
      bf16x8 ar[4], br[4];
#pragma unroll
      for (int f = 0; f < 4; ++f) ar[f] = *(const bf16x8*)(Ab + ks * 8192 + offA[f]);
#pragma unroll
      for (int f = 0; f < 4; ++f) br[f] = *(const bf16x8*)(Bb + ks * 8192 + offB[f]);
      __builtin_amdgcn_s_setprio(1);
#pragma unroll
      for (int mf = 0; mf < 4; ++mf)
#pragma unroll
        for (int nf = 0; nf < 4; ++nf)
          acc[mf][nf] = __builtin_amdgcn_mfma_f32_16x16x32_bf16(ar[mf], br[nf], acc[mf][nf], 0, 0, 0);
      __builtin_amdgcn_s_setprio(0);
    }
    asm volatile("s_waitcnt lgkmcnt(0)" ::: "memory");
    __builtin_amdgcn_s_barrier();
    if (t + 2 < NT) {
      stage_tile(t + 2);
      asm volatile("s_waitcnt vmcnt(8)" ::: "memory");
    } else {
      asm volatile("s_waitcnt vmcnt(0)" ::: "memory");
    }
    __builtin_amdgcn_s_barrier();
  }

  // ---------------- epilogues ----------------
  if constexpr (EPI == 0 || EPI == 1) {
    // packed u32 fp8 stores; d2 within-64-group permuted (pos t holds true (t&3)*16+(t>>2))
    u8* C = (u8*)Cv;
    const int hh = (n0 + wn * 64) >> 9;
    const int d2g = (n0 & 511) + wn * 64;
#pragma unroll
    for (int mf = 0; mf < 4; ++mf)
#pragma unroll
      for (int r = 0; r < 4; ++r) {
        int gm = m0 + wm * 64 + mf * 16 + (g << 2) + r;
        int b = gm >> 9, s = gm & 511;
        float v0 = acc[mf][0][r] + bias[n0 + wn * 64 + 0 * 16 + r16];
        float v1 = acc[mf][1][r] + bias[n0 + wn * 64 + 1 * 16 + r16];
        float v2 = acc[mf][2][r] + bias[n0 + wn * 64 + 2 * 16 + r16];
        float v3 = acc[mf][3][r] + bias[n0 + wn * 64 + 3 * 16 + r16];
        int pk = __builtin_amdgcn_cvt_pk_fp8_f32(v0, v1, 0, false);
        pk = __builtin_amdgcn_cvt_pk_fp8_f32(v2, v3, pk, true);
        int row = (EPI == 0) ? ((s << 3) + hh) : ((hh << 9) + s);
        *(u32*)(C + (size_t)b * 2097152 + (size_t)row * 512 + d2g + r16 * 4) = (u32)pk;
      }
  } else {  // EPI == 2: vpt fp8, transposed, kv-permuted (pos t holds kv=(t&3)*16+(t>>2))
    u16* E = (u16*)smem;   // 128 x 129 bf16
#pragma unroll
    for (int mf = 0; mf < 4; ++mf)
#pragma unroll
      for (int nf = 0; nf < 4; ++nf)
#pragma unroll
        for (int r = 0; r < 4; ++r) {
          int lm = wm * 64 + mf * 16 + (g << 2) + r;
          int ln = wn * 64 + nf * 16 + r16;
          E[lm * 129 + ln] = f2bf(acc[mf][nf][r] + bias[n0 + ln]);
        }
    __syncthreads();
    int b = m0 >> 9, s0 = m0 & 511, hh = n0 >> 9, d20 = n0 & 511;
    u8* C = (u8*)Cv;
    int c = tid >> 1;            // local col (d2), 128 cols, 2 thr/col
    int r0 = (tid & 1) * 64;     // which 64-block of the 128 rows (s)
    u8* dst = C + (size_t)b * 2097152 + (size_t)(d20 + c) * 4096 + (hh << 9) + s0 + r0;
#pragma unroll
    for (int i = 0; i < 64; i += 8) {
      u8x8 p;
#pragma unroll
      for (int jj = 0; jj < 8; ++jj) {
        int t = i + jj;
        int sl = r0 + ((t & 3) << 4) + (t >> 2);   // kv of out-position t
        p[jj] = f2fp8(bf2f(E[sl * 129 + c]));
      }
      *(u8x8*)(dst + i) = p;
    }
  }
}

// =====================================================================
// fp8 pipelined BMxBN B^T GEMM (scores / PV). 512 thr, 8 waves (4M x 2N).
// K-tile = 64 B/row; LDS 2 bufs x (A BM*64 + B BN*64) = 48KB (256x128).
// b128 frag reads (both K-halves, virtual-k reorder, A/B consistent).
// Swizzle: 16B slot x = g ^ ((row>>1)&3)  -> conflict-free.
// EPI: 6 scores  P(u8, kv-permuted packed u32) = exp(s*scale), rowsum L
//      7 PV      O = (P@V)/L -> oflat bf16 (packed u16x4, K-permuted)
// =====================================================================
template<int BM, int BN, int EPI>
__global__ __launch_bounds__(512, 4) void gemm_f8(
    const u8* __restrict__ A, const u8* __restrict__ B, void* __restrict__ Cv,
    float* __restrict__ Lbuf, int N, int K, float scale,
    long bsA, long bsB, long bsC)
{
  constexpr int TILEB = (BM + BN) * 64;
  __shared__ alignas(16) char smem[2 * TILEB];

  const int tid = threadIdx.x, lid = tid & 63, wid = tid >> 6;
  const int wm = wid >> 1, wn = wid & 1;
  const int g = lid >> 4, r16 = lid & 15;

  const int nx = gridDim.x, ny = gridDim.y;
  const int lin = blockIdx.x + nx * (blockIdx.y + ny * blockIdx.z);
  const int xcd = lin & 7, slot = lin >> 3;
  const int wx = slot % nx;
  const int c_ = xcd + (slot / nx) * 8;
  const int m0 = (c_ % ny) * BM, n0 = wx * BN, z = c_ / ny;

  A += (size_t)z * bsA;
  B += (size_t)z * bsB;
  const int NT = K >> 6;

  int offA[4], offB[4];
#pragma unroll
  for (int f = 0; f < 4; ++f) {
    int ra = wm * 64 + f * 16 + r16;
    offA[f] = ra * 64 + ((g ^ ((ra >> 1) & 3)) << 4);
    int rb = wn * 64 + f * 16 + r16;
    offB[f] = rb * 64 + ((g ^ ((rb >> 1) & 3)) << 4);
  }

  auto stage_tile = [&](int ts) {
    char* base = smem + (ts & 1) * TILEB;
    const u8* At = A + (size_t)ts * 64;
    const u8* Bt = B + (size_t)ts * 64;
#pragma unroll
    for (int l = 0; l < BM / 128; ++l) {
      int i = l * 512 + tid;
      int row = i >> 2, x = i & 3;
      int c = x ^ ((row >> 1) & 3);
      gld_lds16(At + (size_t)(m0 + row) * K + c * 16, base + i * 16);
    }
#pragma unroll
    for (int l = 0; l < BN / 128; ++l) {
      int i = l * 512 + tid;
      int row = i >> 2, x = i & 3;
      int c = x ^ ((row >> 1) & 3);
      gld_lds16(Bt + (size_t)(n0 + row) * K + c * 16, base + BM * 64 + i * 16);
    }
  };

  f32x4 acc[4][4];
#pragma unroll
  for (int i = 0; i < 4; ++i)
#pragma unroll
    for (int j = 0; j < 4; ++j) acc[i][j] = 0.0f;

  stage_tile(0);
  stage_tile(1);
  asm volatile("s_waitcnt vmcnt(3)" ::: "memory");
  __builtin_amdgcn_s_barrier();

  for (int t = 0; t < NT; ++t) {
    const char* Ab = smem + (t & 1) * TILEB;
    const char* Bb = Ab + BM * 64;
    lx2 ar[4], br[4];
#pragma unroll
    for (int f = 0; f < 4; ++f) ar[f] = *(const lx2*)(Ab + offA[f]);
#pragma unroll
    for (int f = 0; f < 4; ++f) br[f] = *(const lx2*)(Bb + offB[f]);
    __builtin_amdgcn_s_setprio(1);
#pragma unroll
    for (int mf = 0; mf < 4; ++mf)
#pragma unroll
      for (int nf = 0; nf < 4; ++nf) {
        acc[mf][nf] = __builtin_amdgcn_mfma_f32_16x16x32_fp8_fp8(ar[mf][0], br[nf][0], acc[mf][nf], 0, 0, 0);
        acc[mf][nf] = __builtin_amdgcn_mfma_f32_16x16x32_fp8_fp8(ar[mf][1], br[nf][1], acc[mf][nf], 0, 0, 0);
      }
    __builtin_amdgcn_s_setprio(0);
    asm volatile("s_waitcnt lgkmcnt(0)" ::: "memory");
    __builtin_amdgcn_s_barrier();
    if (t + 2 < NT) {
      stage_tile(t + 2);
      asm volatile("s_waitcnt vmcnt(3)" ::: "memory");
    } else {
      asm volatile("s_waitcnt vmcnt(0)" ::: "memory");
    }
    __builtin_amdgcn_s_barrier();
  }

  if constexpr (EPI == 6) {
    // P = exp(s*scale) -> fp8, kv-permuted packed u32; rowsum L via shfl+atomic
    u8* Cp = (u8*)Cv + (size_t)z * bsC;
    float* Lp = Lbuf + (size_t)z * 4096;
#pragma unroll
    for (int mf = 0; mf < 4; ++mf) {
#pragma unroll
      for (int r = 0; r < 4; ++r) {
        int gm = m0 + wm * 64 + mf * 16 + (g << 2) + r;
        float p0 = __expf(acc[mf][0][r] * scale);
        float p1 = __expf(acc[mf][1][r] * scale);
        float p2 = __expf(acc[mf][2][r] * scale);
        float p3 = __expf(acc[mf][3][r] * scale);
        float rs = (p0 + p1) + (p2 + p3);
        int pk = __builtin_amdgcn_cvt_pk_fp8_f32(p0, p1, 0, false);
        pk = __builtin_amdgcn_cvt_pk_fp8_f32(p2, p3, pk, true);
        *(u32*)(Cp + (size_t)gm * N + n0 + wn * 64 + r16 * 4) = (u32)pk;
        rs += __shfl_xor(rs, 1); rs += __shfl_xor(rs, 2);
        rs += __shfl_xor(rs, 4); rs += __shfl_xor(rs, 8);
        if (r16 == 0) atomicAdd(&Lp[gm], rs);
      }
    }
  } else {
    // PV: O = acc / L[row] -> oflat bf16, packed u16x4, cols within-64 permuted
    u16* C = (u16*)Cv + (size_t)z * bsC;
    const float* Lp = Lbuf + (size_t)z * 4096;
#pragma unroll
    for (int mf = 0; mf < 4; ++mf) {
#pragma unroll
      for (int r = 0; r < 4; ++r) {
        int gm = m0 + wm * 64 + mf * 16 + (g << 2) + r;
        float inv = 1.0f / Lp[gm];
        u16x4 o;
#pragma unroll
        for (int nf = 0; nf < 4; ++nf) o[nf] = f2bf(acc[mf][nf][r] * inv);
        *(u16x4*)(C + (size_t)(gm >> 3) * 4096 + (size_t)(gm & 7) * 512 +
                  n0 + wn * 64 + r16 * 4) = o;
      }
    }
  }
}

// ---------------- final projection, bf16 in, f32+bias out, 64x64 tile ----------------
__global__ __launch_bounds__(256) void gemm_bt_final(
    const u16* __restrict__ A, const u16* __restrict__ B, float* __restrict__ C,
    const float* __restrict__ bias, int N, int K)
{
  constexpr int BM = 64, BN = 64, BK = 64;
  __shared__ alignas(16) char smem[(BM + BN) * BK * 2];
  u16* As = (u16*)smem;
  u16* Bs = As + BM * BK;

  const int tid = threadIdx.x;
  const int lid = tid & 63, wid = tid >> 6;
  const int m0 = blockIdx.y * BM, n0 = blockIdx.x * BN;
  const int wm = wid >> 1, wn = wid & 1;

  f32x4 acc[2][2];
#pragma unroll
  for (int i = 0; i < 2; ++i)
#pragma unroll
    for (int j = 0; j < 2; ++j) acc[i][j] = 0.0f;

  const int rA = lid >> 3;
  const int ke = (lid & 7) * 8;

  const int nK = K / BK;
  for (int kt = 0; kt < nK; ++kt) {
    const int k0 = kt * BK;
#pragma unroll
    for (int c = 0; c < 2; ++c) {
      int chunk = wid * 2 + c;
      gld_lds16(A + (size_t)(m0 + chunk * 8 + rA) * K + k0 + ke, (char*)As + chunk * 1024);
    }
#pragma unroll
    for (int c = 0; c < 2; ++c) {
      int chunk = wid * 2 + c;
      gld_lds16(B + (size_t)(n0 + chunk * 8 + rA) * K + k0 + ke, (char*)Bs + chunk * 1024);
    }
    __syncthreads();
#pragma unroll
    for (int kc = 0; kc < 2; ++kc) {
      bf16x8 af[2], bfv[2];
      const int kb = kc * 32 + (lid >> 4) * 8;
#pragma unroll
      for (int i = 0; i < 2; ++i)
        af[i] = *(const bf16x8*)&As[(wm * 32 + i * 16 + (lid & 15)) * BK + kb];
#pragma unroll
      for (int j = 0; j < 2; ++j)
        bfv[j] = *(const bf16x8*)&Bs[(wn * 32 + j * 16 + (lid & 15)) * BK + kb];
#pragma unroll
      for (int i = 0; i < 2; ++i)
#pragma unroll
        for (int j = 0; j < 2; ++j)
          acc[i][j] = __builtin_amdgcn_mfma_f32_16x16x32_bf16(af[i], bfv[j], acc[i][j], 0, 0, 0);
    }
    __syncthreads();
  }

#pragma unroll
  for (int i = 0; i < 2; ++i)
#pragma unroll
    for (int j = 0; j < 2; ++j)
#pragma unroll
      for (int r = 0; r < 4; ++r) {
        int gm = m0 + wm * 32 + i * 16 + ((lid >> 4) << 2) + r;
        int gn = n0 + wn * 32 + j * 16 + (lid & 15);
        C[(size_t)gm * N + gn] = acc[i][j][r] + bias[gn];
      }
}

// ---------------------------------------------------------------------------
extern "C" void kernel_launch(void* const* d_in, const int* in_sizes, int n_in,
                              void* d_out, int out_size, void* d_ws, size_t ws_size,
                              hipStream_t stream) {
  (void)in_sizes; (void)n_in; (void)out_size; (void)ws_size;
  const float* q_f  = (const float*)d_in[0];
  const float* k_f  = (const float*)d_in[1];
  const float* v_f  = (const float*)d_in[2];
  const float* wq_b = (const float*)d_in[4];
  const float* wk_b = (const float*)d_in[6];
  const float* wv_b = (const float*)d_in[8];
  const float* ou_b = (const float*)d_in[10];
  float* out = (float*)d_out;

  char* ws = (char*)d_ws;
  u16* q_bf  = (u16*)(ws + 0);          // 2MB  bf16(q)
  u16* k_bf  = (u16*)(ws + 2097152);    // 2MB
  u16* v_bf  = (u16*)(ws + 4194304);    // 2MB
  u16* wA_q  = (u16*)(ws + 6291456);    // 4MB  bf16(wk_w) (reference swap)
  u16* wA_k  = (u16*)(ws + 10485760);   // 4MB  bf16(wq_w)
  u16* wA_v  = (u16*)(ws + 14680064);   // 4MB  bf16(wv_w)
  u16* ow_bf = (u16*)(ws + 18874368);   // 4MB  bf16(out_w), K within-64 permuted
  u8*  qp    = (u8*)(ws + 23068672);    // 8MB  (4,4096,512) fp8, l=s*8+h, d2 permuted
  u8*  kp    = (u8*)(ws + 31457280);    // 8MB  (4,4096,512) fp8, l'=h*512+s, d2 permuted
  u8*  vpt   = (u8*)(ws + 39845888);    // 8MB  (4,512,4096) fp8, [d2][kv-permuted]
  u16* oflat = (u16*)(ws + 48234496);   // 16MB (4,512,4096) bf16, cols within-64 permuted
  u8*  P     = (u8*)(ws + 65011712);    // 64MB (4,4096,4096) fp8, cols kv-permuted

  float* L = (float*)d_out;  // 64KB row-sums; dead until final GEMM overwrites

  // converts (bf16 — projections must stay bf16 for accuracy)
  cvt_kernel<<<512,  256, 0, stream>>>(q_f, q_bf, 1048576);
  cvt_kernel<<<512,  256, 0, stream>>>(k_f, k_bf, 1048576);
  cvt_kernel<<<512,  256, 0, stream>>>(v_f, v_bf, 1048576);
  cvt_kernel<<<1024, 256, 0, stream>>>((const float*)d_in[5], wA_q, 2097152);
  cvt_kernel<<<1024, 256, 0, stream>>>((const float*)d_in[3], wA_k, 2097152);
  cvt_kernel<<<1024, 256, 0, stream>>>((const float*)d_in[7], wA_v, 2097152);
  cvt_permK<<<1024, 256, 0, stream>>>((const float*)d_in[9], ow_bf, 2097152);

  // projections in bf16; qp/kp/vpt stored fp8 (reference swap: qp uses wk, kp uses wq)
  gemm_bf<0><<<dim3(32,16,1), 256, 0, stream>>>(q_bf, wA_q, qp,  wk_b, 4096, 512);
  gemm_bf<1><<<dim3(32,16,1), 256, 0, stream>>>(k_bf, wA_k, kp,  wq_b, 4096, 512);
  gemm_bf<2><<<dim3(32,16,1), 256, 0, stream>>>(v_bf, wA_v, vpt, wv_b, 4096, 512);

  const float scl = 0.04419417382415922f;  // 1/sqrt(512)
  hipMemsetAsync(L, 0, 65536, stream);
  // scores: P = exp(s*scl) fp8 (kv-permuted) + row-sums into L   (fp8 operands)
  gemm_f8<256,128,6><<<dim3(32,16,4), 512, 0, stream>>>(qp, kp, P, L, 4096, 512, scl,
                                                        2097152, 2097152, 16777216);
  // PV: O = (P @ V) / L -> oflat bf16   (fp8 operands, matching kv permutation)
  gemm_f8<256,128,7><<<dim3(4,16,4), 512, 0, stream>>>(P, vpt, oflat, L, 512, 4096, 1.f,
                                                       16777216, 2097152, 2097152);
  // final projection, bf16 -> f32 + bias (oflat & ow_bf share the K permutation)
  gemm_bt_final<<<dim3(8,32,1), 256, 0, stream>>>(oflat, ow_bf, out, ou_b, 512, 4096);
}

// Round 9
// 236.960 us; speedup vs baseline: 1.4963x; 1.0259x over previous
//
#include <hip/hip_runtime.h>
#include <cstddef>

typedef unsigned short u16;
typedef unsigned char u8;
typedef unsigned u32;
typedef float f32x4 __attribute__((ext_vector_type(4)));
typedef u16 u16x4 __attribute__((ext_vector_type(4)));
typedef u16 u16x8 __attribute__((ext_vector_type(8)));
typedef u8 u8x8 __attribute__((ext_vector_type(8)));
typedef __bf16 bf16x8 __attribute__((ext_vector_type(8)));
typedef long lx2 __attribute__((ext_vector_type(2)));

__device__ __forceinline__ u16 f2bf(float f) {
  u32 u = __builtin_bit_cast(u32, f);
  u += 0x7fffu + ((u >> 16) & 1u);   // RTNE
  return (u16)(u >> 16);
}
__device__ __forceinline__ float bf2f(u16 h) {
  return __builtin_bit_cast(float, ((u32)h) << 16);
}
__device__ __forceinline__ u8 f2fp8(float v) {
  int t = __builtin_amdgcn_cvt_pk_fp8_f32(v, v, 0, false);
  return (u8)(t & 0xff);
}
__device__ __forceinline__ void gld_lds16(const void* g, void* l) {
  __builtin_amdgcn_global_load_lds((const __attribute__((address_space(1))) void*)g,
                                   (__attribute__((address_space(3))) void*)l, 16, 0, 0);
}

// ---------------- all f32->bf16 converts in ONE launch ----------------
// segs: q(512) k(512) v(512) w5(1024) w3(1024) w7(1024) w9-permK(1024) = 5632 blocks
__global__ __launch_bounds__(256) void cvt_all(
    const float* __restrict__ q, const float* __restrict__ k, const float* __restrict__ v,
    const float* __restrict__ w5, const float* __restrict__ w3,
    const float* __restrict__ w7, const float* __restrict__ w9,
    u16* __restrict__ o_q, u16* __restrict__ o_k, u16* __restrict__ o_v,
    u16* __restrict__ o_wq, u16* __restrict__ o_wk, u16* __restrict__ o_wv,
    u16* __restrict__ o_ow)
{
  int b = blockIdx.x;
  const float* in; u16* out; int base; bool perm = false;
  if      (b < 512)  { in = q;  out = o_q;  base = b; }
  else if (b < 1024) { in = k;  out = o_k;  base = b - 512; }
  else if (b < 1536) { in = v;  out = o_v;  base = b - 1024; }
  else if (b < 2560) { in = w5; out = o_wq; base = b - 1536; }
  else if (b < 3584) { in = w3; out = o_wk; base = b - 2560; }
  else if (b < 4608) { in = w7; out = o_wv; base = b - 3584; }
  else               { in = w9; out = o_ow; base = b - 4608; perm = true; }
  int i = (base * 256 + threadIdx.x) * 8;
  u16x8 o;
  if (!perm) {
    f32x4 a = *(const f32x4*)(in + i);
    f32x4 c = *(const f32x4*)(in + i + 4);
    o[0] = f2bf(a[0]); o[1] = f2bf(a[1]); o[2] = f2bf(a[2]); o[3] = f2bf(a[3]);
    o[4] = f2bf(c[0]); o[5] = f2bf(c[1]); o[6] = f2bf(c[2]); o[7] = f2bf(c[3]);
  } else {
    // within-64 K-group permutation: pos t <- true (t&3)*16+(t>>2)
    int row = i >> 12, col0 = i & 4095;
    int group = col0 & ~63, t0 = col0 & 63;
    const float* rp = in + ((size_t)row << 12) + group;
#pragma unroll
    for (int j = 0; j < 8; ++j) {
      int t = t0 + j;
      o[j] = f2bf(rp[((t & 3) << 4) + (t >> 2)]);
    }
  }
  *(u16x8*)(out + i) = o;
}

// =====================================================================
// bf16 pipelined 128x128 B^T GEMM (projections).  256 thr, 4 waves.
// EPI: 0 qp-proj -> fp8 (d2 within-64 permuted, packed u32 stores)
//      1 kp-proj -> fp8 (same packing)
//      2 vpt-proj -> fp8 transposed + kv-interleave permuted
// =====================================================================
template<int EPI>
__global__ __launch_bounds__(256, 2) void gemm_bf(
    const u16* __restrict__ A, const u16* __restrict__ B, void* __restrict__ Cv,
    const float* __restrict__ bias, int N, int K)
{
  __shared__ alignas(16) char smem[65536];

  const int tid = threadIdx.x, lid = tid & 63, wid = tid >> 6;
  const int wm = wid >> 1, wn = wid & 1;
  const int g = lid >> 4, r16 = lid & 15;

  const int nx = gridDim.x, ny = gridDim.y;
  const int lin = blockIdx.x + nx * blockIdx.y;
  const int xcd = lin & 7, slot = lin >> 3;
  const int wx = slot % nx;
  const int c_ = xcd + (slot / nx) * 8;
  const int m0 = (c_ % ny) * 128, n0 = wx * 128;

  const int NT = K >> 6;

  int offA[4], offB[4];
#pragma unroll
  for (int f = 0; f < 4; ++f) {
    int ra = wm * 64 + f * 16 + r16;
    offA[f] = ra * 64 + ((g ^ ((ra >> 1) & 3)) << 4);
    int rb = wn * 64 + f * 16 + r16;
    offB[f] = rb * 64 + ((g ^ ((rb >> 1) & 3)) << 4);
  }

  auto stage_tile = [&](int ts) {
    char* base = smem + (ts & 1) * 32768;
    const u16* At = A + (size_t)ts * 64;
    const u16* Bt = B + (size_t)ts * 64;
#pragma unroll
    for (int l = 0; l < 4; ++l) {
      int i = l * 256 + tid;
      int ks = i >> 9, rem = i & 511, row = rem >> 2, x = rem & 3;
      int c = x ^ ((row >> 1) & 3);
      gld_lds16(At + (size_t)(m0 + row) * K + ks * 32 + c * 8,
                base + ks * 8192 + rem * 16);
    }
#pragma unroll
    for (int l = 0; l < 4; ++l) {
      int i = l * 256 + tid;
      int ks = i >> 9, rem = i & 511, row = rem >> 2, x = rem & 3;
      int c = x ^ ((row >> 1) & 3);
      gld_lds16(Bt + (size_t)(n0 + row) * K + ks * 32 + c * 8,
                base + 16384 + ks * 8192 + rem * 16);
    }
  };

  f32x4 acc[4][4];
#pragma unroll
  for (int i = 0; i < 4; ++i)
#pragma unroll
    for (int j = 0; j < 4; ++j) acc[i][j] = 0.0f;

  stage_tile(0);
  stage_tile(1);
  asm volatile("s_waitcnt vmcnt(8)" ::: "memory");
  __builtin_amdgcn_s_barrier();

  for (int t = 0; t < NT; ++t) {
    const char* Ab = smem + (t & 1) * 32768;
    const char* Bb = Ab + 16384;
#pragma unroll
    for (int ks = 0; ks < 2; ++ks) {
      bf16x8 ar[4], br[4];
#pragma unroll
      for (int f = 0; f < 4; ++f) ar[f] = *(const bf16x8*)(Ab + ks * 8192 + offA[f]);
#pragma unroll
      for (int f = 0; f < 4; ++f) br[f] = *(const bf16x8*)(Bb + ks * 8192 + offB[f]);
      __builtin_amdgcn_s_setprio(1);
#pragma unroll
      for (int mf = 0; mf < 4; ++mf)
#pragma unroll
        for (int nf = 0; nf < 4; ++nf)
          acc[mf][nf] = __builtin_amdgcn_mfma_f32_16x16x32_bf16(ar[mf], br[nf], acc[mf][nf], 0, 0, 0);
      __builtin_amdgcn_s_setprio(0);
    }
    asm volatile("s_waitcnt lgkmcnt(0)" ::: "memory");
    __builtin_amdgcn_s_barrier();
    if (t + 2 < NT) {
      stage_tile(t + 2);
      asm volatile("s_waitcnt vmcnt(8)" ::: "memory");
    } else {
      asm volatile("s_waitcnt vmcnt(0)" ::: "memory");
    }
    __builtin_amdgcn_s_barrier();
  }

  // ---------------- epilogues ----------------
  if constexpr (EPI == 0 || EPI == 1) {
    u8* C = (u8*)Cv;
    const int hh = (n0 + wn * 64) >> 9;
    const int d2g = (n0 & 511) + wn * 64;
#pragma unroll
    for (int mf = 0; mf < 4; ++mf)
#pragma unroll
      for (int r = 0; r < 4; ++r) {
        int gm = m0 + wm * 64 + mf * 16 + (g << 2) + r;
        int b = gm >> 9, s = gm & 511;
        float v0 = acc[mf][0][r] + bias[n0 + wn * 64 + 0 * 16 + r16];
        float v1 = acc[mf][1][r] + bias[n0 + wn * 64 + 1 * 16 + r16];
        float v2 = acc[mf][2][r] + bias[n0 + wn * 64 + 2 * 16 + r16];
        float v3 = acc[mf][3][r] + bias[n0 + wn * 64 + 3 * 16 + r16];
        int pk = __builtin_amdgcn_cvt_pk_fp8_f32(v0, v1, 0, false);
        pk = __builtin_amdgcn_cvt_pk_fp8_f32(v2, v3, pk, true);
        int row = (EPI == 0) ? ((s << 3) + hh) : ((hh << 9) + s);
        *(u32*)(C + (size_t)b * 2097152 + (size_t)row * 512 + d2g + r16 * 4) = (u32)pk;
      }
  } else {  // EPI == 2: vpt fp8, transposed, kv-permuted
    u16* E = (u16*)smem;   // 128 x 129 bf16
#pragma unroll
    for (int mf = 0; mf < 4; ++mf)
#pragma unroll
      for (int nf = 0; nf < 4; ++nf)
#pragma unroll
        for (int r = 0; r < 4; ++r) {
          int lm = wm * 64 + mf * 16 + (g << 2) + r;
          int ln = wn * 64 + nf * 16 + r16;
          E[lm * 129 + ln] = f2bf(acc[mf][nf][r] + bias[n0 + ln]);
        }
    __syncthreads();
    int b = m0 >> 9, s0 = m0 & 511, hh = n0 >> 9, d20 = n0 & 511;
    u8* C = (u8*)Cv;
    int c = tid >> 1;
    int r0 = (tid & 1) * 64;
    u8* dst = C + (size_t)b * 2097152 + (size_t)(d20 + c) * 4096 + (hh << 9) + s0 + r0;
#pragma unroll
    for (int i = 0; i < 64; i += 8) {
      u8x8 p;
#pragma unroll
      for (int jj = 0; jj < 8; ++jj) {
        int t = i + jj;
        int sl = r0 + ((t & 3) << 4) + (t >> 2);   // kv of out-position t
        p[jj] = f2fp8(bf2f(E[sl * 129 + c]));
      }
      *(u8x8*)(dst + i) = p;
    }
  }
}

// =====================================================================
// fp8 pipelined 128x128 B^T GEMM (scores / PV), 3-SLOT RING, 1 barrier/tile.
// 256 thr, 4 waves (2M x 2N). K-tile 64B. LDS 3 x (A 8KB + B 8KB) = 48KB.
// Per tile: {8 b128 frag reads; stage(t+2)->slot (t+2)%3; MFMA x32;
//            lgkm0 (free); counted vmcnt(4); ONE barrier}.
// Slot(t+2) is read neither in window t nor t+1 -> no drain handoff needed.
// b128 reads = both K-halves (virtual-k); swizzle x = g^((row>>1)&3): 0-conflict.
// EPI: 6 scores  P(u8, kv-permuted packed u32) = exp(s*scale), rowsum L
//      7 PV      O = (P@V)/L -> oflat bf16 (packed u16x4, K-permuted)
// =====================================================================
template<int EPI>
__global__ __launch_bounds__(256, 4) void gemm_f8(
    const u8* __restrict__ A, const u8* __restrict__ B, void* __restrict__ Cv,
    float* __restrict__ Lbuf, int N, int K, float scale,
    long bsA, long bsB, long bsC)
{
  __shared__ alignas(16) char smem[49152];

  const int tid = threadIdx.x, lid = tid & 63, wid = tid >> 6;
  const int wm = wid >> 1, wn = wid & 1;
  const int g = lid >> 4, r16 = lid & 15;

  const int nx = gridDim.x, ny = gridDim.y;
  const int lin = blockIdx.x + nx * (blockIdx.y + ny * blockIdx.z);
  const int xcd = lin & 7, slot = lin >> 3;
  const int wx = slot % nx;
  const int c_ = xcd + (slot / nx) * 8;
  const int m0 = (c_ % ny) * 128, n0 = wx * 128, z = c_ / ny;

  A += (size_t)z * bsA;
  B += (size_t)z * bsB;
  const int NT = K >> 6;

  int offA[4], offB[4];
#pragma unroll
  for (int f = 0; f < 4; ++f) {
    int ra = wm * 64 + f * 16 + r16;
    offA[f] = ra * 64 + ((g ^ ((ra >> 1) & 3)) << 4);
    int rb = wn * 64 + f * 16 + r16;
    offB[f] = rb * 64 + ((g ^ ((rb >> 1) & 3)) << 4);
  }

  auto stage_tile = [&](int ts) {
    char* base = smem + (ts % 3) * 16384;
    const u8* At = A + (size_t)ts * 64;
    const u8* Bt = B + (size_t)ts * 64;
#pragma unroll
    for (int l = 0; l < 2; ++l) {
      int i = l * 256 + tid;
      int row = i >> 2, x = i & 3;
      int c = x ^ ((row >> 1) & 3);
      gld_lds16(At + (size_t)(m0 + row) * K + c * 16, base + i * 16);
    }
#pragma unroll
    for (int l = 0; l < 2; ++l) {
      int i = l * 256 + tid;
      int row = i >> 2, x = i & 3;
      int c = x ^ ((row >> 1) & 3);
      gld_lds16(Bt + (size_t)(n0 + row) * K + c * 16, base + 8192 + i * 16);
    }
  };

  f32x4 acc[4][4];
#pragma unroll
  for (int i = 0; i < 4; ++i)
#pragma unroll
    for (int j = 0; j < 4; ++j) acc[i][j] = 0.0f;

  // prologue: stage tiles 0,1; wait tile0 landed (tile1 in flight)
  stage_tile(0);
  stage_tile(1);
  asm volatile("s_waitcnt vmcnt(4)" ::: "memory");
  __builtin_amdgcn_s_barrier();

  for (int t = 0; t < NT; ++t) {
    const char* Ab = smem + (t % 3) * 16384;
    const char* Bb = Ab + 8192;
    lx2 ar[4], br[4];
#pragma unroll
    for (int f = 0; f < 4; ++f) ar[f] = *(const lx2*)(Ab + offA[f]);
#pragma unroll
    for (int f = 0; f < 4; ++f) br[f] = *(const lx2*)(Bb + offB[f]);
    if (t + 2 < NT) stage_tile(t + 2);
    __builtin_amdgcn_s_setprio(1);
#pragma unroll
    for (int mf = 0; mf < 4; ++mf)
#pragma unroll
      for (int nf = 0; nf < 4; ++nf) {
        acc[mf][nf] = __builtin_amdgcn_mfma_f32_16x16x32_fp8_fp8(ar[mf][0], br[nf][0], acc[mf][nf], 0, 0, 0);
        acc[mf][nf] = __builtin_amdgcn_mfma_f32_16x16x32_fp8_fp8(ar[mf][1], br[nf][1], acc[mf][nf], 0, 0, 0);
      }
    __builtin_amdgcn_s_setprio(0);
    // my reads are consumed; drain residual lgkm (≈free) to close the
    // slot-(t-1) read-vs-future-write window, then certify t+1 landed.
    asm volatile("s_waitcnt lgkmcnt(0)" ::: "memory");
    if (t + 2 < NT)      asm volatile("s_waitcnt vmcnt(4)" ::: "memory");
    else if (t + 1 < NT) asm volatile("s_waitcnt vmcnt(0)" ::: "memory");
    __builtin_amdgcn_s_barrier();
  }

  if constexpr (EPI == 6) {
    // P = exp(s*scale) -> fp8, kv-permuted packed u32; rowsum L via shfl+atomic
    u8* Cp = (u8*)Cv + (size_t)z * bsC;
    float* Lp = Lbuf + (size_t)z * 4096;
#pragma unroll
    for (int mf = 0; mf < 4; ++mf) {
#pragma unroll
      for (int r = 0; r < 4; ++r) {
        int gm = m0 + wm * 64 + mf * 16 + (g << 2) + r;
        float p0 = __expf(acc[mf][0][r] * scale);
        float p1 = __expf(acc[mf][1][r] * scale);
        float p2 = __expf(acc[mf][2][r] * scale);
        float p3 = __expf(acc[mf][3][r] * scale);
        float rs = (p0 + p1) + (p2 + p3);
        int pk = __builtin_amdgcn_cvt_pk_fp8_f32(p0, p1, 0, false);
        pk = __builtin_amdgcn_cvt_pk_fp8_f32(p2, p3, pk, true);
        *(u32*)(Cp + (size_t)gm * N + n0 + wn * 64 + r16 * 4) = (u32)pk;
        rs += __shfl_xor(rs, 1); rs += __shfl_xor(rs, 2);
        rs += __shfl_xor(rs, 4); rs += __shfl_xor(rs, 8);
        if (r16 == 0) atomicAdd(&Lp[gm], rs);
      }
    }
  } else {
    // PV: O = acc / L[row] -> oflat bf16, packed u16x4, cols within-64 permuted
    u16* C = (u16*)Cv + (size_t)z * bsC;
    const float* Lp = Lbuf + (size_t)z * 4096;
#pragma unroll
    for (int mf = 0; mf < 4; ++mf) {
#pragma unroll
      for (int r = 0; r < 4; ++r) {
        int gm = m0 + wm * 64 + mf * 16 + (g << 2) + r;
        float inv = 1.0f / Lp[gm];
        u16x4 o;
#pragma unroll
        for (int nf = 0; nf < 4; ++nf) o[nf] = f2bf(acc[mf][nf][r] * inv);
        *(u16x4*)(C + (size_t)(gm >> 3) * 4096 + (size_t)(gm & 7) * 512 +
                  n0 + wn * 64 + r16 * 4) = o;
      }
    }
  }
}

// ---------------- final projection, bf16 in, f32+bias out, 64x64 tile ----------------
__global__ __launch_bounds__(256) void gemm_bt_final(
    const u16* __restrict__ A, const u16* __restrict__ B, float* __restrict__ C,
    const float* __restrict__ bias, int N, int K)
{
  constexpr int BM = 64, BN = 64, BK = 64;
  __shared__ alignas(16) char smem[(BM + BN) * BK * 2];
  u16* As = (u16*)smem;
  u16* Bs = As + BM * BK;

  const int tid = threadIdx.x;
  const int lid = tid & 63, wid = tid >> 6;
  const int m0 = blockIdx.y * BM, n0 = blockIdx.x * BN;
  const int wm = wid >> 1, wn = wid & 1;

  f32x4 acc[2][2];
#pragma unroll
  for (int i = 0; i < 2; ++i)
#pragma unroll
    for (int j = 0; j < 2; ++j) acc[i][j] = 0.0f;

  const int rA = lid >> 3;
  const int ke = (lid & 7) * 8;

  const int nK = K / BK;
  for (int kt = 0; kt < nK; ++kt) {
    const int k0 = kt * BK;
#pragma unroll
    for (int c = 0; c < 2; ++c) {
      int chunk = wid * 2 + c;
      gld_lds16(A + (size_t)(m0 + chunk * 8 + rA) * K + k0 + ke, (char*)As + chunk * 1024);
    }
#pragma unroll
    for (int c = 0; c < 2; ++c) {
      int chunk = wid * 2 + c;
      gld_lds16(B + (size_t)(n0 + chunk * 8 + rA) * K + k0 + ke, (char*)Bs + chunk * 1024);
    }
    __syncthreads();
#pragma unroll
    for (int kc = 0; kc < 2; ++kc) {
      bf16x8 af[2], bfv[2];
      const int kb = kc * 32 + (lid >> 4) * 8;
#pragma unroll
      for (int i = 0; i < 2; ++i)
        af[i] = *(const bf16x8*)&As[(wm * 32 + i * 16 + (lid & 15)) * BK + kb];
#pragma unroll
      for (int j = 0; j < 2; ++j)
        bfv[j] = *(const bf16x8*)&Bs[(wn * 32 + j * 16 + (lid & 15)) * BK + kb];
#pragma unroll
      for (int i = 0; i < 2; ++i)
#pragma unroll
        for (int j = 0; j < 2; ++j)
          acc[i][j] = __builtin_amdgcn_mfma_f32_16x16x32_bf16(af[i], bfv[j], acc[i][j], 0, 0, 0);
    }
    __syncthreads();
  }

#pragma unroll
  for (int i = 0; i < 2; ++i)
#pragma unroll
    for (int j = 0; j < 2; ++j)
#pragma unroll
      for (int r = 0; r < 4; ++r) {
        int gm = m0 + wm * 32 + i * 16 + ((lid >> 4) << 2) + r;
        int gn = n0 + wn * 32 + j * 16 + (lid & 15);
        C[(size_t)gm * N + gn] = acc[i][j][r] + bias[gn];
      }
}

// ---------------------------------------------------------------------------
extern "C" void kernel_launch(void* const* d_in, const int* in_sizes, int n_in,
                              void* d_out, int out_size, void* d_ws, size_t ws_size,
                              hipStream_t stream) {
  (void)in_sizes; (void)n_in; (void)out_size; (void)ws_size;
  const float* q_f  = (const float*)d_in[0];
  const float* k_f  = (const float*)d_in[1];
  const float* v_f  = (const float*)d_in[2];
  const float* wq_b = (const float*)d_in[4];
  const float* wk_b = (const float*)d_in[6];
  const float* wv_b = (const float*)d_in[8];
  const float* ou_b = (const float*)d_in[10];
  float* out = (float*)d_out;

  char* ws = (char*)d_ws;
  u16* q_bf  = (u16*)(ws + 0);          // 2MB  bf16(q)
  u16* k_bf  = (u16*)(ws + 2097152);    // 2MB
  u16* v_bf  = (u16*)(ws + 4194304);    // 2MB
  u16* wA_q  = (u16*)(ws + 6291456);    // 4MB  bf16(wk_w) (reference swap)
  u16* wA_k  = (u16*)(ws + 10485760);   // 4MB  bf16(wq_w)
  u16* wA_v  = (u16*)(ws + 14680064);   // 4MB  bf16(wv_w)
  u16* ow_bf = (u16*)(ws + 18874368);   // 4MB  bf16(out_w), K within-64 permuted
  u8*  qp    = (u8*)(ws + 23068672);    // 8MB  (4,4096,512) fp8, l=s*8+h, d2 permuted
  u8*  kp    = (u8*)(ws + 31457280);    // 8MB  (4,4096,512) fp8, l'=h*512+s, d2 permuted
  u8*  vpt   = (u8*)(ws + 39845888);    // 8MB  (4,512,4096) fp8, [d2][kv-permuted]
  u16* oflat = (u16*)(ws + 48234496);   // 16MB (4,512,4096) bf16, cols within-64 permuted
  u8*  P     = (u8*)(ws + 65011712);    // 64MB (4,4096,4096) fp8, cols kv-permuted

  float* L = (float*)d_out;  // 64KB row-sums; dead until final GEMM overwrites

  // all converts in one launch
  cvt_all<<<5632, 256, 0, stream>>>(
      q_f, k_f, v_f, (const float*)d_in[5], (const float*)d_in[3],
      (const float*)d_in[7], (const float*)d_in[9],
      q_bf, k_bf, v_bf, wA_q, wA_k, wA_v, ow_bf);

  // projections in bf16; qp/kp/vpt stored fp8 (reference swap: qp uses wk, kp uses wq)
  gemm_bf<0><<<dim3(32,16,1), 256, 0, stream>>>(q_bf, wA_q, qp,  wk_b, 4096, 512);
  gemm_bf<1><<<dim3(32,16,1), 256, 0, stream>>>(k_bf, wA_k, kp,  wq_b, 4096, 512);
  gemm_bf<2><<<dim3(32,16,1), 256, 0, stream>>>(v_bf, wA_v, vpt, wv_b, 4096, 512);

  const float scl = 0.04419417382415922f;  // 1/sqrt(512)
  hipMemsetAsync(L, 0, 65536, stream);
  // scores: P = exp(s*scl) fp8 (kv-permuted) + row-sums into L   (fp8 operands)
  gemm_f8<6><<<dim3(32,32,4), 256, 0, stream>>>(qp, kp, P, L, 4096, 512, scl,
                                                2097152, 2097152, 16777216);
  // PV: O = (P @ V) / L -> oflat bf16   (fp8 operands, matching kv permutation)
  gemm_f8<7><<<dim3(4,32,4), 256, 0, stream>>>(P, vpt, oflat, L, 512, 4096, 1.f,
                                               16777216, 2097152, 2097152);
  // final projection, bf16 -> f32 + bias (oflat & ow_bf share the K permutation)
  gemm_bt_final<<<dim3(8,32,1), 256, 0, stream>>>(oflat, ow_bf, out, ou_b, 512, 4096);
}